// Round 1
// baseline (3967.383 us; speedup 1.0000x reference)
//
#include <hip/hip_runtime.h>
#include <math.h>

#define N_NODES 50000
#define N_EDGES 800000
#define IN_CH 128

// ---------------------------------------------------------------------------
// degree: deg[dst] += 1 for every edge
// ---------------------------------------------------------------------------
__global__ void deg_kernel(const int* __restrict__ dst, float* __restrict__ deg, int nE) {
    int i = blockIdx.x * blockDim.x + threadIdx.x;
    if (i < nE) atomicAdd(&deg[dst[i]], 1.0f);
}

// ---------------------------------------------------------------------------
// fused double GEMM: pl = in @ Wl ; pr = in @ Wr + b
// in: [nNodes, 128] row-major, Wl/Wr: [128, D_OUT] row-major
// block = 256 threads, NPB = 256/D_OUT nodes per block
// ---------------------------------------------------------------------------
template <int D_OUT>
__global__ __launch_bounds__(256) void gemm2_kernel(
    const float* __restrict__ in, const float* __restrict__ Wl,
    const float* __restrict__ Wr, const float* __restrict__ b,
    float* __restrict__ pl, float* __restrict__ pr, int nNodes) {
    constexpr int NPB = 256 / D_OUT;
    __shared__ float xs[NPB][IN_CH];
    const int tid = threadIdx.x;
    const int node0 = blockIdx.x * NPB;

    // cooperative load of NPB node rows into LDS (float4 vectorized)
    constexpr int TOTAL4 = NPB * IN_CH / 4;  // float4 elements
    for (int idx = tid; idx < TOTAL4; idx += 256) {
        int nn = idx / (IN_CH / 4);
        int kk = idx % (IN_CH / 4);
        int node = node0 + nn;
        float4 v = make_float4(0.f, 0.f, 0.f, 0.f);
        if (node < nNodes) v = *(const float4*)&in[(long long)node * IN_CH + kk * 4];
        *(float4*)&xs[nn][kk * 4] = v;
    }
    __syncthreads();

    const int nn = tid / D_OUT;
    const int o = tid % D_OUT;
    const int node = node0 + nn;
    if (node >= nNodes) return;

    float al = 0.f, ar = 0.f;
#pragma unroll
    for (int k = 0; k < IN_CH; ++k) {
        float xv = xs[nn][k];  // broadcast within wave
        al = fmaf(xv, Wl[k * D_OUT + o], al);
        ar = fmaf(xv, Wr[k * D_OUT + o], ar);
    }
    pl[(long long)node * D_OUT + o] = al;
    pr[(long long)node * D_OUT + o] = ar + b[o];
}

// ---------------------------------------------------------------------------
// scatter: agg[dst] += pl[src], vectorized float4 per thread
// ---------------------------------------------------------------------------
template <int D_OUT>
__global__ __launch_bounds__(256) void scatter_kernel(
    const int* __restrict__ src, const int* __restrict__ dst,
    const float* __restrict__ pl, float* __restrict__ agg, int nE) {
    constexpr int VPE = D_OUT / 4;  // float4 groups per edge
    long long i = (long long)blockIdx.x * blockDim.x + threadIdx.x;
    long long total = (long long)nE * VPE;
    if (i >= total) return;
    int e = (int)(i / VPE);
    int g = (int)(i % VPE);
    int s = src[e];
    int d = dst[e];
    float4 v = *(const float4*)&pl[(long long)s * D_OUT + g * 4];
    float* base = &agg[(long long)d * D_OUT + g * 4];
    atomicAdd(base + 0, v.x);
    atomicAdd(base + 1, v.y);
    atomicAdd(base + 2, v.z);
    atomicAdd(base + 3, v.w);
}

// ---------------------------------------------------------------------------
// finalize: out = agg/max(deg,1) + pr  (+ELU)
// ---------------------------------------------------------------------------
template <int D_OUT, bool ELU>
__global__ __launch_bounds__(256) void finalize_kernel(
    const float* __restrict__ agg, const float* __restrict__ pr,
    const float* __restrict__ deg, float* __restrict__ out, int nNodes) {
    long long i = (long long)blockIdx.x * blockDim.x + threadIdx.x;
    if (i >= (long long)nNodes * D_OUT) return;
    int node = (int)(i / D_OUT);
    float inv = 1.0f / fmaxf(deg[node], 1.0f);
    float v = agg[i] * inv + pr[i];
    if (ELU) v = v > 0.f ? v : expm1f(v);
    out[i] = v;
}

// ---------------------------------------------------------------------------
extern "C" void kernel_launch(void* const* d_in, const int* in_sizes, int n_in,
                              void* d_out, int out_size, void* d_ws, size_t ws_size,
                              hipStream_t stream) {
    const float* x = (const float*)d_in[0];
    const int* ei = (const int*)d_in[1];  // [2, N_EDGES] int32
    const int* src = ei;
    const int* dst = ei + N_EDGES;
    const float* Wl0 = (const float*)d_in[2];
    const float* Wr0 = (const float*)d_in[3];
    const float* b0 = (const float*)d_in[4];
    const float* Wl1 = (const float*)d_in[5];
    const float* Wr1 = (const float*)d_in[6];
    const float* b1 = (const float*)d_in[7];
    const float* Wl2 = (const float*)d_in[8];
    const float* Wr2 = (const float*)d_in[9];
    const float* b2 = (const float*)d_in[10];
    float* out = (float*)d_out;

    // workspace layout (floats)
    float* ws = (float*)d_ws;
    const long long NB = (long long)N_NODES * 128;  // big buffer elems
    float* deg = ws;             // [51200] (padded)
    float* pl = ws + 51200;      // [N*128]
    float* pr = pl + NB;         // [N*128]
    float* agg = pr + NB;        // [N*128]
    float* h = agg + NB;         // [N*128]

    // degree (once; same edges for all layers)
    hipMemsetAsync(deg, 0, N_NODES * sizeof(float), stream);
    deg_kernel<<<(N_EDGES + 255) / 256, 256, 0, stream>>>(dst, deg, N_EDGES);

    // ---- layer 0: x -> h (d_out = 128, ELU) ----
    hipMemsetAsync(agg, 0, NB * sizeof(float), stream);
    gemm2_kernel<128><<<N_NODES / 2, 256, 0, stream>>>(x, Wl0, Wr0, b0, pl, pr, N_NODES);
    {
        long long total = (long long)N_EDGES * (128 / 4);
        scatter_kernel<128><<<(int)((total + 255) / 256), 256, 0, stream>>>(src, dst, pl, agg, N_EDGES);
    }
    finalize_kernel<128, true><<<(int)((NB + 255) / 256), 256, 0, stream>>>(agg, pr, deg, h, N_NODES);

    // ---- layer 1: h -> h (d_out = 128, ELU) ----
    hipMemsetAsync(agg, 0, NB * sizeof(float), stream);
    gemm2_kernel<128><<<N_NODES / 2, 256, 0, stream>>>(h, Wl1, Wr1, b1, pl, pr, N_NODES);
    {
        long long total = (long long)N_EDGES * (128 / 4);
        scatter_kernel<128><<<(int)((total + 255) / 256), 256, 0, stream>>>(src, dst, pl, agg, N_EDGES);
    }
    finalize_kernel<128, true><<<(int)((NB + 255) / 256), 256, 0, stream>>>(agg, pr, deg, h, N_NODES);

    // ---- layer 2: h -> out (d_out = 64, no ELU) ----
    const long long NB2 = (long long)N_NODES * 64;
    hipMemsetAsync(agg, 0, NB2 * sizeof(float), stream);
    gemm2_kernel<64><<<N_NODES / 4, 256, 0, stream>>>(h, Wl2, Wr2, b2, pl, pr, N_NODES);
    {
        long long total = (long long)N_EDGES * (64 / 4);
        scatter_kernel<64><<<(int)((total + 255) / 256), 256, 0, stream>>>(src, dst, pl, agg, N_EDGES);
    }
    finalize_kernel<64, false><<<(int)((NB2 + 255) / 256), 256, 0, stream>>>(agg, pr, deg, out, N_NODES);
}

// Round 2
// 812.588 us; speedup vs baseline: 4.8824x; 4.8824x over previous
//
#include <hip/hip_runtime.h>
#include <math.h>

#define N_NODES 50000
#define N_EDGES 800000
#define IN_CH 128

// ---------------------------------------------------------------------------
// degree count (int) per destination node
// ---------------------------------------------------------------------------
__global__ void deg_kernel(const int* __restrict__ dst, int* __restrict__ degi, int nE) {
    int i = blockIdx.x * blockDim.x + threadIdx.x;
    if (i < nE) atomicAdd(&degi[dst[i]], 1);
}

// ---------------------------------------------------------------------------
// single-block exclusive scan: degi[0..n) -> offs[0..n], cursor = copy of offs
// ---------------------------------------------------------------------------
#define SCAN_T 1024
__global__ __launch_bounds__(SCAN_T) void scan_kernel(
    const int* __restrict__ degi, int* __restrict__ offs,
    int* __restrict__ cursor, int n) {
    __shared__ int part[SCAN_T];
    const int t = threadIdx.x;
    const int chunk = (n + SCAN_T - 1) / SCAN_T;
    const int lo = min(t * chunk, n), hi = min(lo + chunk, n);
    int s = 0;
    for (int i = lo; i < hi; ++i) s += degi[i];
    part[t] = s;
    __syncthreads();
    for (int d = 1; d < SCAN_T; d <<= 1) {
        int v = (t >= d) ? part[t - d] : 0;
        __syncthreads();
        part[t] += v;
        __syncthreads();
    }
    int run = (t == 0) ? 0 : part[t - 1];
    for (int i = lo; i < hi; ++i) {
        offs[i] = run;
        cursor[i] = run;
        run += degi[i];
    }
    if (t == SCAN_T - 1) offs[n] = part[SCAN_T - 1];
}

// ---------------------------------------------------------------------------
// CSR bucket fill: ebuf[cursor[dst]++] = src
// ---------------------------------------------------------------------------
__global__ void fill_kernel(const int* __restrict__ src, const int* __restrict__ dst,
                            int* __restrict__ cursor, int* __restrict__ ebuf, int nE) {
    int e = blockIdx.x * blockDim.x + threadIdx.x;
    if (e < nE) {
        int p = atomicAdd(&cursor[dst[e]], 1);
        ebuf[p] = src[e];
    }
}

// ---------------------------------------------------------------------------
// fused double GEMM: pl = in @ Wl ; pr = in @ Wr + b
// ---------------------------------------------------------------------------
template <int D_OUT>
__global__ __launch_bounds__(256) void gemm2_kernel(
    const float* __restrict__ in, const float* __restrict__ Wl,
    const float* __restrict__ Wr, const float* __restrict__ b,
    float* __restrict__ pl, float* __restrict__ pr, int nNodes) {
    constexpr int NPB = 256 / D_OUT;
    __shared__ float xs[NPB][IN_CH];
    const int tid = threadIdx.x;
    const int node0 = blockIdx.x * NPB;

    constexpr int TOTAL4 = NPB * IN_CH / 4;
    for (int idx = tid; idx < TOTAL4; idx += 256) {
        int nn = idx / (IN_CH / 4);
        int kk = idx % (IN_CH / 4);
        int node = node0 + nn;
        float4 v = make_float4(0.f, 0.f, 0.f, 0.f);
        if (node < nNodes) v = *(const float4*)&in[(long long)node * IN_CH + kk * 4];
        *(float4*)&xs[nn][kk * 4] = v;
    }
    __syncthreads();

    const int nn = tid / D_OUT;
    const int o = tid % D_OUT;
    const int node = node0 + nn;
    if (node >= nNodes) return;

    float al = 0.f, ar = 0.f;
#pragma unroll
    for (int k = 0; k < IN_CH; ++k) {
        float xv = xs[nn][k];
        al = fmaf(xv, Wl[k * D_OUT + o], al);
        ar = fmaf(xv, Wr[k * D_OUT + o], ar);
    }
    pl[(long long)node * D_OUT + o] = al;
    pr[(long long)node * D_OUT + o] = ar + b[o];
}

// ---------------------------------------------------------------------------
// gather + finalize: one wave per dst node.
// out[node] = (sum_{s in CSR[node]} pl[s]) / max(deg,1) + pr[node]  (+ELU)
// ---------------------------------------------------------------------------
template <int D_OUT, bool ELU>
__global__ __launch_bounds__(256) void gather_kernel(
    const int* __restrict__ offs, const int* __restrict__ ebuf,
    const float* __restrict__ pl, const float* __restrict__ pr,
    float* __restrict__ out, int nNodes) {
    const int wid = (int)((blockIdx.x * 256u + threadIdx.x) >> 6);
    const int lane = threadIdx.x & 63;
    if (wid >= nNodes) return;
    const int o0 = offs[wid], o1 = offs[wid + 1];
    const float inv = 1.0f / fmaxf((float)(o1 - o0), 1.0f);

    if constexpr (D_OUT == 128) {
        const int c = lane * 2;
        float ax0 = 0, ay0 = 0, ax1 = 0, ay1 = 0, ax2 = 0, ay2 = 0, ax3 = 0, ay3 = 0;
        int j = o0;
        for (; j + 4 <= o1; j += 4) {
            int s0 = ebuf[j], s1 = ebuf[j + 1], s2 = ebuf[j + 2], s3 = ebuf[j + 3];
            float2 v0 = *(const float2*)&pl[(size_t)s0 * 128 + c];
            float2 v1 = *(const float2*)&pl[(size_t)s1 * 128 + c];
            float2 v2 = *(const float2*)&pl[(size_t)s2 * 128 + c];
            float2 v3 = *(const float2*)&pl[(size_t)s3 * 128 + c];
            ax0 += v0.x; ay0 += v0.y;
            ax1 += v1.x; ay1 += v1.y;
            ax2 += v2.x; ay2 += v2.y;
            ax3 += v3.x; ay3 += v3.y;
        }
        for (; j < o1; ++j) {
            int s0 = ebuf[j];
            float2 v0 = *(const float2*)&pl[(size_t)s0 * 128 + c];
            ax0 += v0.x; ay0 += v0.y;
        }
        float vx = (ax0 + ax1 + ax2 + ax3) * inv + pr[(size_t)wid * 128 + c];
        float vy = (ay0 + ay1 + ay2 + ay3) * inv + pr[(size_t)wid * 128 + c + 1];
        if (ELU) {
            vx = vx > 0.f ? vx : expm1f(vx);
            vy = vy > 0.f ? vy : expm1f(vy);
        }
        float2 r; r.x = vx; r.y = vy;
        *(float2*)&out[(size_t)wid * 128 + c] = r;
    } else {  // D_OUT == 64
        const int c = lane;
        float a0 = 0, a1 = 0, a2 = 0, a3 = 0;
        int j = o0;
        for (; j + 4 <= o1; j += 4) {
            int s0 = ebuf[j], s1 = ebuf[j + 1], s2 = ebuf[j + 2], s3 = ebuf[j + 3];
            a0 += pl[(size_t)s0 * 64 + c];
            a1 += pl[(size_t)s1 * 64 + c];
            a2 += pl[(size_t)s2 * 64 + c];
            a3 += pl[(size_t)s3 * 64 + c];
        }
        for (; j < o1; ++j) a0 += pl[(size_t)ebuf[j] * 64 + c];
        float v = (a0 + a1 + a2 + a3) * inv + pr[(size_t)wid * 64 + c];
        if (ELU) v = v > 0.f ? v : expm1f(v);
        out[(size_t)wid * 64 + c] = v;
    }
}

// ---------------------------------------------------------------------------
extern "C" void kernel_launch(void* const* d_in, const int* in_sizes, int n_in,
                              void* d_out, int out_size, void* d_ws, size_t ws_size,
                              hipStream_t stream) {
    const float* x = (const float*)d_in[0];
    const int* ei = (const int*)d_in[1];
    const int* src = ei;
    const int* dst = ei + N_EDGES;
    const float* Wl0 = (const float*)d_in[2];
    const float* Wr0 = (const float*)d_in[3];
    const float* b0 = (const float*)d_in[4];
    const float* Wl1 = (const float*)d_in[5];
    const float* Wr1 = (const float*)d_in[6];
    const float* b1 = (const float*)d_in[7];
    const float* Wl2 = (const float*)d_in[8];
    const float* Wr2 = (const float*)d_in[9];
    const float* b2 = (const float*)d_in[10];
    float* out = (float*)d_out;

    // workspace layout
    char* wsb = (char*)d_ws;
    int* degi = (int*)wsb;                   // [51200]
    int* offs = degi + 51200;                // [51200]
    int* cursor = offs + 51200;              // [51200]
    int* ebuf = cursor + 51200;              // [800000]
    float* pl = (float*)(ebuf + 800000);     // [N*128]
    const long long NB = (long long)N_NODES * 128;
    float* pr = pl + NB;                     // [N*128]
    float* h = pr + NB;                      // [N*128]

    // ---- build CSR (once; same edges for all layers) ----
    hipMemsetAsync(degi, 0, N_NODES * sizeof(int), stream);
    deg_kernel<<<(N_EDGES + 255) / 256, 256, 0, stream>>>(dst, degi, N_EDGES);
    scan_kernel<<<1, SCAN_T, 0, stream>>>(degi, offs, cursor, N_NODES);
    fill_kernel<<<(N_EDGES + 255) / 256, 256, 0, stream>>>(src, dst, cursor, ebuf, N_EDGES);

    const int GATHER_GRID = (N_NODES * 64 + 255) / 256;  // one wave per node

    // ---- layer 0: x -> h ----
    gemm2_kernel<128><<<N_NODES / 2, 256, 0, stream>>>(x, Wl0, Wr0, b0, pl, pr, N_NODES);
    gather_kernel<128, true><<<GATHER_GRID, 256, 0, stream>>>(offs, ebuf, pl, pr, h, N_NODES);

    // ---- layer 1: h -> h ----
    gemm2_kernel<128><<<N_NODES / 2, 256, 0, stream>>>(h, Wl1, Wr1, b1, pl, pr, N_NODES);
    gather_kernel<128, true><<<GATHER_GRID, 256, 0, stream>>>(offs, ebuf, pl, pr, h, N_NODES);

    // ---- layer 2: h -> out ----
    gemm2_kernel<64><<<N_NODES / 4, 256, 0, stream>>>(h, Wl2, Wr2, b2, pl, pr, N_NODES);
    gather_kernel<64, false><<<GATHER_GRID, 256, 0, stream>>>(offs, ebuf, pl, pr, out, N_NODES);
}

// Round 3
// 494.858 us; speedup vs baseline: 8.0172x; 1.6421x over previous
//
#include <hip/hip_runtime.h>
#include <math.h>

#define N_NODES 50000
#define N_EDGES 800000
#define IN_CH 128

typedef unsigned short ushort_t;
typedef unsigned int uint_t;

static __device__ __forceinline__ ushort_t f32_to_bf16(float f) {
    uint_t u = __float_as_uint(f);
    uint_t r = (u + 0x7fffu + ((u >> 16) & 1u)) >> 16;  // RNE
    return (ushort_t)r;
}

// ---------------------------------------------------------------------------
// degree count (int) per destination node
// ---------------------------------------------------------------------------
__global__ void deg_kernel(const int* __restrict__ dst, int* __restrict__ degi, int nE) {
    int i = blockIdx.x * blockDim.x + threadIdx.x;
    if (i < nE) atomicAdd(&degi[dst[i]], 1);
}

// ---------------------------------------------------------------------------
// single-block exclusive scan: degi[0..n) -> offs[0..n], cursor = copy
// ---------------------------------------------------------------------------
#define SCAN_T 1024
__global__ __launch_bounds__(SCAN_T) void scan_kernel(
    const int* __restrict__ degi, int* __restrict__ offs,
    int* __restrict__ cursor, int n) {
    __shared__ int part[SCAN_T];
    const int t = threadIdx.x;
    const int chunk = (n + SCAN_T - 1) / SCAN_T;
    const int lo = min(t * chunk, n), hi = min(lo + chunk, n);
    int s = 0;
    for (int i = lo; i < hi; ++i) s += degi[i];
    part[t] = s;
    __syncthreads();
    for (int d = 1; d < SCAN_T; d <<= 1) {
        int v = (t >= d) ? part[t - d] : 0;
        __syncthreads();
        part[t] += v;
        __syncthreads();
    }
    int run = (t == 0) ? 0 : part[t - 1];
    for (int i = lo; i < hi; ++i) {
        offs[i] = run;
        cursor[i] = run;
        run += degi[i];
    }
    if (t == SCAN_T - 1) offs[n] = part[SCAN_T - 1];
}

// ---------------------------------------------------------------------------
// CSR bucket fill: ebuf[cursor[dst]++] = src
// ---------------------------------------------------------------------------
__global__ void fill_kernel(const int* __restrict__ src, const int* __restrict__ dst,
                            int* __restrict__ cursor, int* __restrict__ ebuf, int nE) {
    int e = blockIdx.x * blockDim.x + threadIdx.x;
    if (e < nE) {
        int p = atomicAdd(&cursor[dst[e]], 1);
        ebuf[p] = src[e];
    }
}

// ---------------------------------------------------------------------------
// register-blocked double GEMM: pl = in @ Wl ; pr = in @ Wr + b
// BM nodes per block, thread tile = NPT nodes x 4 Wl-out x 4 Wr-out.
// PL_BF16: store pl as bf16 (ushort) for the gather.
// ---------------------------------------------------------------------------
template <int D_OUT, int BM, bool PL_BF16>
__global__ __launch_bounds__(256) void gemm2_kernel(
    const float* __restrict__ in, const float* __restrict__ Wl,
    const float* __restrict__ Wr, const float* __restrict__ b,
    void* __restrict__ pl_v, float* __restrict__ pr, int nNodes) {
    constexpr int TO = D_OUT / 4;   // threads along output dim
    constexpr int TN = 256 / TO;    // threads along node dim
    constexpr int NPT = BM / TN;    // nodes per thread
    __shared__ float xs[BM][IN_CH];
    const int tid = threadIdx.x;
    const int node0 = blockIdx.x * BM;

    // cooperative load of BM node rows (float4)
    for (int idx = tid; idx < BM * (IN_CH / 4); idx += 256) {
        int nn = idx / (IN_CH / 4);
        int kk = idx % (IN_CH / 4);
        int node = node0 + nn;
        float4 v = make_float4(0.f, 0.f, 0.f, 0.f);
        if (node < nNodes) v = *(const float4*)&in[(size_t)node * IN_CH + kk * 4];
        *(float4*)&xs[nn][kk * 4] = v;
    }
    __syncthreads();

    const int to = tid % TO, tn = tid / TO;
    const int o4 = to * 4;
    const int n0 = tn * NPT;

    float accL[NPT][4] = {{0.f}};
    float accR[NPT][4] = {{0.f}};

    for (int k = 0; k < IN_CH; k += 4) {
        float4 xv[NPT];
#pragma unroll
        for (int i = 0; i < NPT; ++i) xv[i] = *(const float4*)&xs[n0 + i][k];
#pragma unroll
        for (int kk = 0; kk < 4; ++kk) {
            float4 wl = *(const float4*)&Wl[(size_t)(k + kk) * D_OUT + o4];
            float4 wr = *(const float4*)&Wr[(size_t)(k + kk) * D_OUT + o4];
#pragma unroll
            for (int i = 0; i < NPT; ++i) {
                float x = ((const float*)&xv[i])[kk];
                accL[i][0] = fmaf(x, wl.x, accL[i][0]);
                accL[i][1] = fmaf(x, wl.y, accL[i][1]);
                accL[i][2] = fmaf(x, wl.z, accL[i][2]);
                accL[i][3] = fmaf(x, wl.w, accL[i][3]);
                accR[i][0] = fmaf(x, wr.x, accR[i][0]);
                accR[i][1] = fmaf(x, wr.y, accR[i][1]);
                accR[i][2] = fmaf(x, wr.z, accR[i][2]);
                accR[i][3] = fmaf(x, wr.w, accR[i][3]);
            }
        }
    }

    const float4 bv = *(const float4*)&b[o4];
#pragma unroll
    for (int i = 0; i < NPT; ++i) {
        int node = node0 + n0 + i;
        if (node >= nNodes) continue;
        if (PL_BF16) {
            ushort4 pk;
            pk.x = f32_to_bf16(accL[i][0]);
            pk.y = f32_to_bf16(accL[i][1]);
            pk.z = f32_to_bf16(accL[i][2]);
            pk.w = f32_to_bf16(accL[i][3]);
            *(ushort4*)&((ushort_t*)pl_v)[(size_t)node * D_OUT + o4] = pk;
        } else {
            float4 fv;
            fv.x = accL[i][0]; fv.y = accL[i][1]; fv.z = accL[i][2]; fv.w = accL[i][3];
            *(float4*)&((float*)pl_v)[(size_t)node * D_OUT + o4] = fv;
        }
        float4 rv;
        rv.x = accR[i][0] + bv.x;
        rv.y = accR[i][1] + bv.y;
        rv.z = accR[i][2] + bv.z;
        rv.w = accR[i][3] + bv.w;
        *(float4*)&pr[(size_t)node * D_OUT + o4] = rv;
    }
}

// ---------------------------------------------------------------------------
// gather + finalize, D=128, pl is bf16: one wave per dst node, lane owns 2 ch.
// ---------------------------------------------------------------------------
template <bool ELU>
__global__ __launch_bounds__(256) void gather128_bf16_kernel(
    const int* __restrict__ offs, const int* __restrict__ ebuf,
    const ushort_t* __restrict__ pl, const float* __restrict__ pr,
    float* __restrict__ out, int nNodes) {
    const int wid = (int)((blockIdx.x * 256u + threadIdx.x) >> 6);
    const int lane = threadIdx.x & 63;
    if (wid >= nNodes) return;
    const int o0 = offs[wid], o1 = offs[wid + 1];
    const float inv = 1.0f / fmaxf((float)(o1 - o0), 1.0f);
    const int c = lane * 2;

    float ax0 = 0, ay0 = 0, ax1 = 0, ay1 = 0, ax2 = 0, ay2 = 0, ax3 = 0, ay3 = 0;
    int j = o0;
    for (; j + 4 <= o1; j += 4) {
        int s0 = ebuf[j], s1 = ebuf[j + 1], s2 = ebuf[j + 2], s3 = ebuf[j + 3];
        uint_t v0 = *(const uint_t*)&pl[(size_t)s0 * 128 + c];
        uint_t v1 = *(const uint_t*)&pl[(size_t)s1 * 128 + c];
        uint_t v2 = *(const uint_t*)&pl[(size_t)s2 * 128 + c];
        uint_t v3 = *(const uint_t*)&pl[(size_t)s3 * 128 + c];
        ax0 += __uint_as_float(v0 << 16); ay0 += __uint_as_float(v0 & 0xffff0000u);
        ax1 += __uint_as_float(v1 << 16); ay1 += __uint_as_float(v1 & 0xffff0000u);
        ax2 += __uint_as_float(v2 << 16); ay2 += __uint_as_float(v2 & 0xffff0000u);
        ax3 += __uint_as_float(v3 << 16); ay3 += __uint_as_float(v3 & 0xffff0000u);
    }
    for (; j < o1; ++j) {
        uint_t v0 = *(const uint_t*)&pl[(size_t)ebuf[j] * 128 + c];
        ax0 += __uint_as_float(v0 << 16);
        ay0 += __uint_as_float(v0 & 0xffff0000u);
    }
    float vx = (ax0 + ax1 + ax2 + ax3) * inv + pr[(size_t)wid * 128 + c];
    float vy = (ay0 + ay1 + ay2 + ay3) * inv + pr[(size_t)wid * 128 + c + 1];
    if (ELU) {
        vx = vx > 0.f ? vx : expm1f(vx);
        vy = vy > 0.f ? vy : expm1f(vy);
    }
    float2 r; r.x = vx; r.y = vy;
    *(float2*)&out[(size_t)wid * 128 + c] = r;
}

// ---------------------------------------------------------------------------
// gather + finalize, D=64, pl f32: one wave per dst node, lane owns 1 ch.
// ---------------------------------------------------------------------------
__global__ __launch_bounds__(256) void gather64_kernel(
    const int* __restrict__ offs, const int* __restrict__ ebuf,
    const float* __restrict__ pl, const float* __restrict__ pr,
    float* __restrict__ out, int nNodes) {
    const int wid = (int)((blockIdx.x * 256u + threadIdx.x) >> 6);
    const int lane = threadIdx.x & 63;
    if (wid >= nNodes) return;
    const int o0 = offs[wid], o1 = offs[wid + 1];
    const float inv = 1.0f / fmaxf((float)(o1 - o0), 1.0f);
    const int c = lane;
    float a0 = 0, a1 = 0, a2 = 0, a3 = 0;
    int j = o0;
    for (; j + 4 <= o1; j += 4) {
        int s0 = ebuf[j], s1 = ebuf[j + 1], s2 = ebuf[j + 2], s3 = ebuf[j + 3];
        a0 += pl[(size_t)s0 * 64 + c];
        a1 += pl[(size_t)s1 * 64 + c];
        a2 += pl[(size_t)s2 * 64 + c];
        a3 += pl[(size_t)s3 * 64 + c];
    }
    for (; j < o1; ++j) a0 += pl[(size_t)ebuf[j] * 64 + c];
    float v = (a0 + a1 + a2 + a3) * inv + pr[(size_t)wid * 64 + c];
    out[(size_t)wid * 64 + c] = v;
}

// ---------------------------------------------------------------------------
extern "C" void kernel_launch(void* const* d_in, const int* in_sizes, int n_in,
                              void* d_out, int out_size, void* d_ws, size_t ws_size,
                              hipStream_t stream) {
    const float* x = (const float*)d_in[0];
    const int* ei = (const int*)d_in[1];
    const int* src = ei;
    const int* dst = ei + N_EDGES;
    const float* Wl0 = (const float*)d_in[2];
    const float* Wr0 = (const float*)d_in[3];
    const float* b0 = (const float*)d_in[4];
    const float* Wl1 = (const float*)d_in[5];
    const float* Wr1 = (const float*)d_in[6];
    const float* b1 = (const float*)d_in[7];
    const float* Wl2 = (const float*)d_in[8];
    const float* Wr2 = (const float*)d_in[9];
    const float* b2 = (const float*)d_in[10];
    float* out = (float*)d_out;

    // workspace layout
    char* wsb = (char*)d_ws;
    int* degi = (int*)wsb;                   // [51200]
    int* offs = degi + 51200;                // [51200]
    int* cursor = offs + 51200;              // [51200]
    int* ebuf = cursor + 51200;              // [800000]
    float* pl = (float*)(ebuf + 800000);     // [N*128] f32 (bf16 uses low half)
    const long long NB = (long long)N_NODES * 128;
    float* pr = pl + NB;                     // [N*128]
    float* h = pr + NB;                      // [N*128]

    // ---- build CSR (once; same edges for all layers) ----
    hipMemsetAsync(degi, 0, N_NODES * sizeof(int), stream);
    deg_kernel<<<(N_EDGES + 255) / 256, 256, 0, stream>>>(dst, degi, N_EDGES);
    scan_kernel<<<1, SCAN_T, 0, stream>>>(degi, offs, cursor, N_NODES);
    fill_kernel<<<(N_EDGES + 255) / 256, 256, 0, stream>>>(src, dst, cursor, ebuf, N_EDGES);

    const int GATHER_GRID = (N_NODES * 64 + 255) / 256;  // one wave per node

    // ---- layer 0: x -> h ----
    gemm2_kernel<128, 32, true><<<(N_NODES + 31) / 32, 256, 0, stream>>>(
        x, Wl0, Wr0, b0, pl, pr, N_NODES);
    gather128_bf16_kernel<true><<<GATHER_GRID, 256, 0, stream>>>(
        offs, ebuf, (const ushort_t*)pl, pr, h, N_NODES);

    // ---- layer 1: h -> h ----
    gemm2_kernel<128, 32, true><<<(N_NODES + 31) / 32, 256, 0, stream>>>(
        h, Wl1, Wr1, b1, pl, pr, N_NODES);
    gather128_bf16_kernel<true><<<GATHER_GRID, 256, 0, stream>>>(
        offs, ebuf, (const ushort_t*)pl, pr, h, N_NODES);

    // ---- layer 2: h -> out ----
    gemm2_kernel<64, 64, false><<<(N_NODES + 63) / 64, 256, 0, stream>>>(
        h, Wl2, Wr2, b2, pl, pr, N_NODES);
    gather64_kernel<<<GATHER_GRID, 256, 0, stream>>>(offs, ebuf, pl, pr, out, N_NODES);
}

// Round 4
// 392.762 us; speedup vs baseline: 10.1012x; 1.2599x over previous
//
#include <hip/hip_runtime.h>
#include <math.h>

#define N_NODES 50000
#define N_EDGES 800000
#define IN_CH 128

typedef unsigned short ushort_t;
typedef unsigned int uint_t;

static __device__ __forceinline__ ushort_t f32_to_bf16(float f) {
    uint_t u = __float_as_uint(f);
    uint_t r = (u + 0x7fffu + ((u >> 16) & 1u)) >> 16;  // RNE
    return (ushort_t)r;
}

// ---------------------------------------------------------------------------
// degree count (int) per destination node
// ---------------------------------------------------------------------------
__global__ void deg_kernel(const int* __restrict__ dst, int* __restrict__ degi, int nE) {
    int i = blockIdx.x * blockDim.x + threadIdx.x;
    if (i < nE) atomicAdd(&degi[dst[i]], 1);
}

// ---------------------------------------------------------------------------
// multi-block exclusive scan, phase 1: per-block sum of 256 degrees
// ---------------------------------------------------------------------------
__global__ __launch_bounds__(256) void scan_p1(const int* __restrict__ degi,
                                               int* __restrict__ bsum, int n) {
    __shared__ int s[256];
    const int t = threadIdx.x;
    const int i = blockIdx.x * 256 + t;
    s[t] = (i < n) ? degi[i] : 0;
    __syncthreads();
    for (int d = 128; d > 0; d >>= 1) {
        if (t < d) s[t] += s[t + d];
        __syncthreads();
    }
    if (t == 0) bsum[blockIdx.x] = s[0];
}

// ---------------------------------------------------------------------------
// phase 2: single-block exclusive scan of block sums (nb <= 256)
// ---------------------------------------------------------------------------
__global__ __launch_bounds__(256) void scan_p2(int* __restrict__ bsum, int nb) {
    __shared__ int s[256];
    const int t = threadIdx.x;
    int v = (t < nb) ? bsum[t] : 0;
    s[t] = v;
    __syncthreads();
    for (int d = 1; d < 256; d <<= 1) {
        int u = (t >= d) ? s[t - d] : 0;
        __syncthreads();
        s[t] += u;
        __syncthreads();
    }
    if (t < nb) bsum[t] = s[t] - v;  // exclusive
}

// ---------------------------------------------------------------------------
// phase 3: per-block exclusive scan + base, write offs and cursor
// ---------------------------------------------------------------------------
__global__ __launch_bounds__(256) void scan_p3(const int* __restrict__ degi,
                                               const int* __restrict__ bsum,
                                               int* __restrict__ offs,
                                               int* __restrict__ cursor, int n) {
    __shared__ int s[256];
    const int t = threadIdx.x;
    const int i = blockIdx.x * 256 + t;
    int v = (i < n) ? degi[i] : 0;
    s[t] = v;
    __syncthreads();
    for (int d = 1; d < 256; d <<= 1) {
        int u = (t >= d) ? s[t - d] : 0;
        __syncthreads();
        s[t] += u;
        __syncthreads();
    }
    if (i < n) {
        int excl = s[t] - v + bsum[blockIdx.x];
        offs[i] = excl;
        cursor[i] = excl;
    }
    if (i == 0) offs[n] = N_EDGES;
}

// ---------------------------------------------------------------------------
// CSR bucket fill: ebuf[cursor[dst]++] = src
// ---------------------------------------------------------------------------
__global__ void fill_kernel(const int* __restrict__ src, const int* __restrict__ dst,
                            int* __restrict__ cursor, int* __restrict__ ebuf, int nE) {
    int e = blockIdx.x * blockDim.x + threadIdx.x;
    if (e < nE) {
        int p = atomicAdd(&cursor[dst[e]], 1);
        ebuf[p] = src[e];
    }
}

// ---------------------------------------------------------------------------
// register-blocked double GEMM: pl = in @ Wl ; pr = in @ Wr + b
// ---------------------------------------------------------------------------
template <int D_OUT, int BM, bool PL_BF16>
__global__ __launch_bounds__(256) void gemm2_kernel(
    const float* __restrict__ in, const float* __restrict__ Wl,
    const float* __restrict__ Wr, const float* __restrict__ b,
    void* __restrict__ pl_v, float* __restrict__ pr, int nNodes) {
    constexpr int TO = D_OUT / 4;   // threads along output dim
    constexpr int TN = 256 / TO;    // threads along node dim
    constexpr int NPT = BM / TN;    // nodes per thread
    __shared__ float xs[BM][IN_CH];
    const int tid = threadIdx.x;
    const int node0 = blockIdx.x * BM;

    for (int idx = tid; idx < BM * (IN_CH / 4); idx += 256) {
        int nn = idx / (IN_CH / 4);
        int kk = idx % (IN_CH / 4);
        int node = node0 + nn;
        float4 v = make_float4(0.f, 0.f, 0.f, 0.f);
        if (node < nNodes) v = *(const float4*)&in[(size_t)node * IN_CH + kk * 4];
        *(float4*)&xs[nn][kk * 4] = v;
    }
    __syncthreads();

    const int to = tid % TO, tn = tid / TO;
    const int o4 = to * 4;
    const int n0 = tn * NPT;

    float accL[NPT][4] = {{0.f}};
    float accR[NPT][4] = {{0.f}};

    for (int k = 0; k < IN_CH; k += 4) {
        float4 xv[NPT];
#pragma unroll
        for (int i = 0; i < NPT; ++i) xv[i] = *(const float4*)&xs[n0 + i][k];
#pragma unroll
        for (int kk = 0; kk < 4; ++kk) {
            float4 wl = *(const float4*)&Wl[(size_t)(k + kk) * D_OUT + o4];
            float4 wr = *(const float4*)&Wr[(size_t)(k + kk) * D_OUT + o4];
#pragma unroll
            for (int i = 0; i < NPT; ++i) {
                float x = ((const float*)&xv[i])[kk];
                accL[i][0] = fmaf(x, wl.x, accL[i][0]);
                accL[i][1] = fmaf(x, wl.y, accL[i][1]);
                accL[i][2] = fmaf(x, wl.z, accL[i][2]);
                accL[i][3] = fmaf(x, wl.w, accL[i][3]);
                accR[i][0] = fmaf(x, wr.x, accR[i][0]);
                accR[i][1] = fmaf(x, wr.y, accR[i][1]);
                accR[i][2] = fmaf(x, wr.z, accR[i][2]);
                accR[i][3] = fmaf(x, wr.w, accR[i][3]);
            }
        }
    }

    const float4 bv = *(const float4*)&b[o4];
#pragma unroll
    for (int i = 0; i < NPT; ++i) {
        int node = node0 + n0 + i;
        if (node >= nNodes) continue;
        if (PL_BF16) {
            ushort4 pk;
            pk.x = f32_to_bf16(accL[i][0]);
            pk.y = f32_to_bf16(accL[i][1]);
            pk.z = f32_to_bf16(accL[i][2]);
            pk.w = f32_to_bf16(accL[i][3]);
            *(ushort4*)&((ushort_t*)pl_v)[(size_t)node * D_OUT + o4] = pk;
        } else {
            float4 fv;
            fv.x = accL[i][0]; fv.y = accL[i][1]; fv.z = accL[i][2]; fv.w = accL[i][3];
            *(float4*)&((float*)pl_v)[(size_t)node * D_OUT + o4] = fv;
        }
        float4 rv;
        rv.x = accR[i][0] + bv.x;
        rv.y = accR[i][1] + bv.y;
        rv.z = accR[i][2] + bv.z;
        rv.w = accR[i][3] + bv.w;
        *(float4*)&pr[(size_t)node * D_OUT + o4] = rv;
    }
}

// ---------------------------------------------------------------------------
// gather + finalize, D=128, pl is bf16: one wave per dst node, lane owns 2 ch.
// ---------------------------------------------------------------------------
template <bool ELU>
__global__ __launch_bounds__(256) void gather128_bf16_kernel(
    const int* __restrict__ offs, const int* __restrict__ ebuf,
    const ushort_t* __restrict__ pl, const float* __restrict__ pr,
    float* __restrict__ out, int nNodes) {
    const int wid = (int)((blockIdx.x * 256u + threadIdx.x) >> 6);
    const int lane = threadIdx.x & 63;
    if (wid >= nNodes) return;
    const int o0 = offs[wid], o1 = offs[wid + 1];
    const float inv = 1.0f / fmaxf((float)(o1 - o0), 1.0f);
    const int c = lane * 2;

    float ax0 = 0, ay0 = 0, ax1 = 0, ay1 = 0, ax2 = 0, ay2 = 0, ax3 = 0, ay3 = 0;
    int j = o0;
    for (; j + 4 <= o1; j += 4) {
        int s0 = ebuf[j], s1 = ebuf[j + 1], s2 = ebuf[j + 2], s3 = ebuf[j + 3];
        uint_t v0 = *(const uint_t*)&pl[(size_t)s0 * 128 + c];
        uint_t v1 = *(const uint_t*)&pl[(size_t)s1 * 128 + c];
        uint_t v2 = *(const uint_t*)&pl[(size_t)s2 * 128 + c];
        uint_t v3 = *(const uint_t*)&pl[(size_t)s3 * 128 + c];
        ax0 += __uint_as_float(v0 << 16); ay0 += __uint_as_float(v0 & 0xffff0000u);
        ax1 += __uint_as_float(v1 << 16); ay1 += __uint_as_float(v1 & 0xffff0000u);
        ax2 += __uint_as_float(v2 << 16); ay2 += __uint_as_float(v2 & 0xffff0000u);
        ax3 += __uint_as_float(v3 << 16); ay3 += __uint_as_float(v3 & 0xffff0000u);
    }
    for (; j < o1; ++j) {
        uint_t v0 = *(const uint_t*)&pl[(size_t)ebuf[j] * 128 + c];
        ax0 += __uint_as_float(v0 << 16);
        ay0 += __uint_as_float(v0 & 0xffff0000u);
    }
    float vx = (ax0 + ax1 + ax2 + ax3) * inv + pr[(size_t)wid * 128 + c];
    float vy = (ay0 + ay1 + ay2 + ay3) * inv + pr[(size_t)wid * 128 + c + 1];
    if (ELU) {
        vx = vx > 0.f ? vx : expm1f(vx);
        vy = vy > 0.f ? vy : expm1f(vy);
    }
    float2 r; r.x = vx; r.y = vy;
    *(float2*)&out[(size_t)wid * 128 + c] = r;
}

// ---------------------------------------------------------------------------
// gather + finalize, D=64, pl f32: one wave per dst node, lane owns 1 ch.
// ---------------------------------------------------------------------------
__global__ __launch_bounds__(256) void gather64_kernel(
    const int* __restrict__ offs, const int* __restrict__ ebuf,
    const float* __restrict__ pl, const float* __restrict__ pr,
    float* __restrict__ out, int nNodes) {
    const int wid = (int)((blockIdx.x * 256u + threadIdx.x) >> 6);
    const int lane = threadIdx.x & 63;
    if (wid >= nNodes) return;
    const int o0 = offs[wid], o1 = offs[wid + 1];
    const float inv = 1.0f / fmaxf((float)(o1 - o0), 1.0f);
    const int c = lane;
    float a0 = 0, a1 = 0, a2 = 0, a3 = 0;
    int j = o0;
    for (; j + 4 <= o1; j += 4) {
        int s0 = ebuf[j], s1 = ebuf[j + 1], s2 = ebuf[j + 2], s3 = ebuf[j + 3];
        a0 += pl[(size_t)s0 * 64 + c];
        a1 += pl[(size_t)s1 * 64 + c];
        a2 += pl[(size_t)s2 * 64 + c];
        a3 += pl[(size_t)s3 * 64 + c];
    }
    for (; j < o1; ++j) a0 += pl[(size_t)ebuf[j] * 64 + c];
    float v = (a0 + a1 + a2 + a3) * inv + pr[(size_t)wid * 64 + c];
    out[(size_t)wid * 64 + c] = v;
}

// ---------------------------------------------------------------------------
extern "C" void kernel_launch(void* const* d_in, const int* in_sizes, int n_in,
                              void* d_out, int out_size, void* d_ws, size_t ws_size,
                              hipStream_t stream) {
    const float* x = (const float*)d_in[0];
    const int* ei = (const int*)d_in[1];
    const int* src = ei;
    const int* dst = ei + N_EDGES;
    const float* Wl0 = (const float*)d_in[2];
    const float* Wr0 = (const float*)d_in[3];
    const float* b0 = (const float*)d_in[4];
    const float* Wl1 = (const float*)d_in[5];
    const float* Wr1 = (const float*)d_in[6];
    const float* b1 = (const float*)d_in[7];
    const float* Wl2 = (const float*)d_in[8];
    const float* Wr2 = (const float*)d_in[9];
    const float* b2 = (const float*)d_in[10];
    float* out = (float*)d_out;

    // workspace layout
    char* wsb = (char*)d_ws;
    int* degi = (int*)wsb;                   // [51200]
    int* offs = degi + 51200;                // [51200]
    int* cursor = offs + 51200;              // [51200]
    int* bsum = cursor + 51200;              // [256]
    int* ebuf = bsum + 256;                  // [800000]
    float* pl = (float*)(ebuf + 800000);     // [N*128] f32 (bf16 uses low half)
    const long long NB = (long long)N_NODES * 128;
    float* pr = pl + NB;                     // [N*128]
    float* h = pr + NB;                      // [N*128]

    const int NSB = (N_NODES + 255) / 256;   // 196 scan blocks

    // ---- build CSR (once; same edges for all layers) ----
    hipMemsetAsync(degi, 0, N_NODES * sizeof(int), stream);
    deg_kernel<<<(N_EDGES + 255) / 256, 256, 0, stream>>>(dst, degi, N_EDGES);
    scan_p1<<<NSB, 256, 0, stream>>>(degi, bsum, N_NODES);
    scan_p2<<<1, 256, 0, stream>>>(bsum, NSB);
    scan_p3<<<NSB, 256, 0, stream>>>(degi, bsum, offs, cursor, N_NODES);
    fill_kernel<<<(N_EDGES + 255) / 256, 256, 0, stream>>>(src, dst, cursor, ebuf, N_EDGES);

    const int GATHER_GRID = (N_NODES * 64 + 255) / 256;  // one wave per node

    // ---- layer 0: x -> h ----
    gemm2_kernel<128, 32, true><<<(N_NODES + 31) / 32, 256, 0, stream>>>(
        x, Wl0, Wr0, b0, pl, pr, N_NODES);
    gather128_bf16_kernel<true><<<GATHER_GRID, 256, 0, stream>>>(
        offs, ebuf, (const ushort_t*)pl, pr, h, N_NODES);

    // ---- layer 1: h -> h ----
    gemm2_kernel<128, 32, true><<<(N_NODES + 31) / 32, 256, 0, stream>>>(
        h, Wl1, Wr1, b1, pl, pr, N_NODES);
    gather128_bf16_kernel<true><<<GATHER_GRID, 256, 0, stream>>>(
        offs, ebuf, (const ushort_t*)pl, pr, h, N_NODES);

    // ---- layer 2: h -> out ----
    gemm2_kernel<64, 64, false><<<(N_NODES + 63) / 64, 256, 0, stream>>>(
        h, Wl2, Wr2, b2, pl, pr, N_NODES);
    gather64_kernel<<<GATHER_GRID, 256, 0, stream>>>(offs, ebuf, pl, pr, out, N_NODES);
}

// Round 5
// 307.474 us; speedup vs baseline: 12.9031x; 1.2774x over previous
//
#include <hip/hip_runtime.h>
#include <math.h>

#define N_NODES 50000
#define N_EDGES 800000
#define IN_CH 128

typedef unsigned short ushort_t;
typedef unsigned int uint_t;
typedef __attribute__((ext_vector_type(8))) short bf16x8;
typedef __attribute__((ext_vector_type(4))) float f32x4;

static __device__ __forceinline__ ushort_t f32_to_bf16(float f) {
    uint_t u = __float_as_uint(f);
    uint_t r = (u + 0x7fffu + ((u >> 16) & 1u)) >> 16;  // RNE
    return (ushort_t)r;
}

static __device__ __forceinline__ bf16x8 cvt8(const float* __restrict__ p) {
    float4 lo = *(const float4*)p;
    float4 hi = *(const float4*)(p + 4);
    bf16x8 r;
    r[0] = (short)f32_to_bf16(lo.x); r[1] = (short)f32_to_bf16(lo.y);
    r[2] = (short)f32_to_bf16(lo.z); r[3] = (short)f32_to_bf16(lo.w);
    r[4] = (short)f32_to_bf16(hi.x); r[5] = (short)f32_to_bf16(hi.y);
    r[6] = (short)f32_to_bf16(hi.z); r[7] = (short)f32_to_bf16(hi.w);
    return r;
}

// ---------------------------------------------------------------------------
// degree count (int) per destination node
// ---------------------------------------------------------------------------
__global__ void deg_kernel(const int* __restrict__ dst, int* __restrict__ degi, int nE) {
    int i = blockIdx.x * blockDim.x + threadIdx.x;
    if (i < nE) atomicAdd(&degi[dst[i]], 1);
}

// ---------------------------------------------------------------------------
// multi-block exclusive scan
// ---------------------------------------------------------------------------
__global__ __launch_bounds__(256) void scan_p1(const int* __restrict__ degi,
                                               int* __restrict__ bsum, int n) {
    __shared__ int s[256];
    const int t = threadIdx.x;
    const int i = blockIdx.x * 256 + t;
    s[t] = (i < n) ? degi[i] : 0;
    __syncthreads();
    for (int d = 128; d > 0; d >>= 1) {
        if (t < d) s[t] += s[t + d];
        __syncthreads();
    }
    if (t == 0) bsum[blockIdx.x] = s[0];
}

__global__ __launch_bounds__(256) void scan_p2(int* __restrict__ bsum, int nb) {
    __shared__ int s[256];
    const int t = threadIdx.x;
    int v = (t < nb) ? bsum[t] : 0;
    s[t] = v;
    __syncthreads();
    for (int d = 1; d < 256; d <<= 1) {
        int u = (t >= d) ? s[t - d] : 0;
        __syncthreads();
        s[t] += u;
        __syncthreads();
    }
    if (t < nb) bsum[t] = s[t] - v;  // exclusive
}

__global__ __launch_bounds__(256) void scan_p3(const int* __restrict__ degi,
                                               const int* __restrict__ bsum,
                                               int* __restrict__ offs,
                                               int* __restrict__ cursor, int n) {
    __shared__ int s[256];
    const int t = threadIdx.x;
    const int i = blockIdx.x * 256 + t;
    int v = (i < n) ? degi[i] : 0;
    s[t] = v;
    __syncthreads();
    for (int d = 1; d < 256; d <<= 1) {
        int u = (t >= d) ? s[t - d] : 0;
        __syncthreads();
        s[t] += u;
        __syncthreads();
    }
    if (i < n) {
        int excl = s[t] - v + bsum[blockIdx.x];
        offs[i] = excl;
        cursor[i] = excl;
    }
    if (i == 0) offs[n] = N_EDGES;
}

// ---------------------------------------------------------------------------
// CSR bucket fill
// ---------------------------------------------------------------------------
__global__ void fill_kernel(const int* __restrict__ src, const int* __restrict__ dst,
                            int* __restrict__ cursor, int* __restrict__ ebuf, int nE) {
    int e = blockIdx.x * blockDim.x + threadIdx.x;
    if (e < nE) {
        int p = atomicAdd(&cursor[dst[e]], 1);
        ebuf[p] = src[e];
    }
}

// ---------------------------------------------------------------------------
// weight prep: Bt[c][k] = bf16( c < D ? Wl[k][c] : Wr[k][c-D] ), K-contiguous
// ---------------------------------------------------------------------------
template <int D_OUT>
__global__ __launch_bounds__(256) void prep_w(const float* __restrict__ Wl,
                                              const float* __restrict__ Wr,
                                              ushort_t* __restrict__ Bt) {
    int i = blockIdx.x * 256 + threadIdx.x;
    if (i >= 2 * D_OUT * IN_CH) return;
    int c = i / IN_CH, k = i % IN_CH;
    float v = (c < D_OUT) ? Wl[(size_t)k * D_OUT + c] : Wr[(size_t)k * D_OUT + (c - D_OUT)];
    Bt[i] = f32_to_bf16(v);
}

// ---------------------------------------------------------------------------
// MFMA double GEMM: [64 nodes] x [2*D_OUT cols (Wl||Wr)] per block, 4 waves.
// pl = in @ Wl (bf16 or f32 out), pr = in @ Wr + b (f32 out).
// A fragments direct from global (row-major, 8 contiguous k per lane);
// B fragments from K-contiguous Bt.
// ---------------------------------------------------------------------------
template <int D_OUT, bool IN_F32, bool PL_F32>
__global__ __launch_bounds__(256) void gemm_mfma(
    const void* __restrict__ in_v, const ushort_t* __restrict__ Bt,
    const float* __restrict__ bias,
    void* __restrict__ pl_v, float* __restrict__ pr, int nNodes) {
    constexpr int C = 2 * D_OUT;
    constexpr int SLAB = C / 4;    // cols per wave
    constexpr int NI = SLAB / 16;  // 16-col subtiles per wave
    const int tid = threadIdx.x;
    const int wave = tid >> 6, lane = tid & 63;
    const int node0 = blockIdx.x * 64;
    const int wcol0 = wave * SLAB;
    const int lrow = lane & 15;
    const int lgrp = lane >> 4;

    const ushort_t* inb = (const ushort_t*)in_v;
    const float* inf = (const float*)in_v;

    f32x4 acc[4][NI] = {};

    for (int ks = 0; ks < 4; ++ks) {
        const int k0 = ks * 32 + lgrp * 8;
        bf16x8 a[4];
#pragma unroll
        for (int mi = 0; mi < 4; ++mi) {
            int r = node0 + mi * 16 + lrow;
            r = min(r, nNodes - 1);
            if (IN_F32) {
                a[mi] = cvt8(&inf[(size_t)r * IN_CH + k0]);
            } else {
                a[mi] = *(const bf16x8*)&inb[(size_t)r * IN_CH + k0];
            }
        }
        bf16x8 bf[NI];
#pragma unroll
        for (int ni = 0; ni < NI; ++ni) {
            int c = wcol0 + ni * 16 + lrow;
            bf[ni] = *(const bf16x8*)&Bt[(size_t)c * IN_CH + k0];
        }
#pragma unroll
        for (int mi = 0; mi < 4; ++mi)
#pragma unroll
            for (int ni = 0; ni < NI; ++ni)
                acc[mi][ni] = __builtin_amdgcn_mfma_f32_16x16x32_bf16(
                    a[mi], bf[ni], acc[mi][ni], 0, 0, 0);
    }

    // epilogue: C/D layout col=lane&15, row=(lane>>4)*4+reg (m89-verified)
    const bool is_pr = (wcol0 >= D_OUT);  // wave-uniform
#pragma unroll
    for (int ni = 0; ni < NI; ++ni) {
        const int c = wcol0 + ni * 16 + lrow;
        const float bv = is_pr ? bias[c - D_OUT] : 0.f;
#pragma unroll
        for (int mi = 0; mi < 4; ++mi) {
#pragma unroll
            for (int j = 0; j < 4; ++j) {
                int r = node0 + mi * 16 + lgrp * 4 + j;
                if (r >= nNodes) continue;
                float v = acc[mi][ni][j];
                if (is_pr) {
                    pr[(size_t)r * D_OUT + (c - D_OUT)] = v + bv;
                } else if (PL_F32) {
                    ((float*)pl_v)[(size_t)r * D_OUT + c] = v;
                } else {
                    ((ushort_t*)pl_v)[(size_t)r * D_OUT + c] = f32_to_bf16(v);
                }
            }
        }
    }
}

// ---------------------------------------------------------------------------
// gather + finalize, D=128, pl bf16, h output bf16: one wave per dst node.
// ---------------------------------------------------------------------------
__global__ __launch_bounds__(256) void gather128_bf16_kernel(
    const int* __restrict__ offs, const int* __restrict__ ebuf,
    const ushort_t* __restrict__ pl, const float* __restrict__ pr,
    ushort_t* __restrict__ out, int nNodes) {
    const int wid = (int)((blockIdx.x * 256u + threadIdx.x) >> 6);
    const int lane = threadIdx.x & 63;
    if (wid >= nNodes) return;
    const int o0 = offs[wid], o1 = offs[wid + 1];
    const float inv = 1.0f / fmaxf((float)(o1 - o0), 1.0f);
    const int c = lane * 2;

    float ax0 = 0, ay0 = 0, ax1 = 0, ay1 = 0, ax2 = 0, ay2 = 0, ax3 = 0, ay3 = 0;
    int j = o0;
    for (; j + 4 <= o1; j += 4) {
        int s0 = ebuf[j], s1 = ebuf[j + 1], s2 = ebuf[j + 2], s3 = ebuf[j + 3];
        uint_t v0 = *(const uint_t*)&pl[(size_t)s0 * 128 + c];
        uint_t v1 = *(const uint_t*)&pl[(size_t)s1 * 128 + c];
        uint_t v2 = *(const uint_t*)&pl[(size_t)s2 * 128 + c];
        uint_t v3 = *(const uint_t*)&pl[(size_t)s3 * 128 + c];
        ax0 += __uint_as_float(v0 << 16); ay0 += __uint_as_float(v0 & 0xffff0000u);
        ax1 += __uint_as_float(v1 << 16); ay1 += __uint_as_float(v1 & 0xffff0000u);
        ax2 += __uint_as_float(v2 << 16); ay2 += __uint_as_float(v2 & 0xffff0000u);
        ax3 += __uint_as_float(v3 << 16); ay3 += __uint_as_float(v3 & 0xffff0000u);
    }
    for (; j < o1; ++j) {
        uint_t v0 = *(const uint_t*)&pl[(size_t)ebuf[j] * 128 + c];
        ax0 += __uint_as_float(v0 << 16);
        ay0 += __uint_as_float(v0 & 0xffff0000u);
    }
    float vx = (ax0 + ax1 + ax2 + ax3) * inv + pr[(size_t)wid * 128 + c];
    float vy = (ay0 + ay1 + ay2 + ay3) * inv + pr[(size_t)wid * 128 + c + 1];
    vx = vx > 0.f ? vx : expm1f(vx);
    vy = vy > 0.f ? vy : expm1f(vy);
    uint_t packed = (uint_t)f32_to_bf16(vx) | ((uint_t)f32_to_bf16(vy) << 16);
    *(uint_t*)&out[(size_t)wid * 128 + c] = packed;
}

// ---------------------------------------------------------------------------
// gather + finalize, D=64, pl f32, f32 out, no ELU (last layer)
// ---------------------------------------------------------------------------
__global__ __launch_bounds__(256) void gather64_kernel(
    const int* __restrict__ offs, const int* __restrict__ ebuf,
    const float* __restrict__ pl, const float* __restrict__ pr,
    float* __restrict__ out, int nNodes) {
    const int wid = (int)((blockIdx.x * 256u + threadIdx.x) >> 6);
    const int lane = threadIdx.x & 63;
    if (wid >= nNodes) return;
    const int o0 = offs[wid], o1 = offs[wid + 1];
    const float inv = 1.0f / fmaxf((float)(o1 - o0), 1.0f);
    const int c = lane;
    float a0 = 0, a1 = 0, a2 = 0, a3 = 0;
    int j = o0;
    for (; j + 4 <= o1; j += 4) {
        int s0 = ebuf[j], s1 = ebuf[j + 1], s2 = ebuf[j + 2], s3 = ebuf[j + 3];
        a0 += pl[(size_t)s0 * 64 + c];
        a1 += pl[(size_t)s1 * 64 + c];
        a2 += pl[(size_t)s2 * 64 + c];
        a3 += pl[(size_t)s3 * 64 + c];
    }
    for (; j < o1; ++j) a0 += pl[(size_t)ebuf[j] * 64 + c];
    float v = (a0 + a1 + a2 + a3) * inv + pr[(size_t)wid * 64 + c];
    out[(size_t)wid * 64 + c] = v;
}

// ---------------------------------------------------------------------------
extern "C" void kernel_launch(void* const* d_in, const int* in_sizes, int n_in,
                              void* d_out, int out_size, void* d_ws, size_t ws_size,
                              hipStream_t stream) {
    const float* x = (const float*)d_in[0];
    const int* ei = (const int*)d_in[1];
    const int* src = ei;
    const int* dst = ei + N_EDGES;
    const float* Wl0 = (const float*)d_in[2];
    const float* Wr0 = (const float*)d_in[3];
    const float* b0 = (const float*)d_in[4];
    const float* Wl1 = (const float*)d_in[5];
    const float* Wr1 = (const float*)d_in[6];
    const float* b1 = (const float*)d_in[7];
    const float* Wl2 = (const float*)d_in[8];
    const float* Wr2 = (const float*)d_in[9];
    const float* b2 = (const float*)d_in[10];
    float* out = (float*)d_out;

    // workspace layout (int units)
    int* wsi = (int*)d_ws;
    int* degi = wsi;                          // 51200
    int* offs = degi + 51200;                 // 51200
    int* cursor = offs + 51200;               // 51200
    int* bsum = cursor + 51200;               // 256
    int* ebuf = bsum + 256;                   // 800000
    ushort_t* Bt0 = (ushort_t*)(ebuf + 800000);   // 256*128 bf16
    ushort_t* Bt1 = Bt0 + 256 * 128;              // 256*128
    ushort_t* Bt2 = Bt1 + 256 * 128;              // 128*128
    float* pl = (float*)(Bt2 + 128 * 128);        // [N*128] f32 (bf16 uses half)
    const long long NB = (long long)N_NODES * 128;
    float* pr = pl + NB;                          // [N*128] f32
    ushort_t* h = (ushort_t*)(pr + NB);           // [N*128] bf16

    const int NSB = (N_NODES + 255) / 256;

    // ---- build CSR (once; shared across layers) ----
    hipMemsetAsync(degi, 0, N_NODES * sizeof(int), stream);
    deg_kernel<<<(N_EDGES + 255) / 256, 256, 0, stream>>>(dst, degi, N_EDGES);
    scan_p1<<<NSB, 256, 0, stream>>>(degi, bsum, N_NODES);
    scan_p2<<<1, 256, 0, stream>>>(bsum, NSB);
    scan_p3<<<NSB, 256, 0, stream>>>(degi, bsum, offs, cursor, N_NODES);
    fill_kernel<<<(N_EDGES + 255) / 256, 256, 0, stream>>>(src, dst, cursor, ebuf, N_EDGES);

    // ---- pack weights to bf16 K-contiguous ----
    prep_w<128><<<(2 * 128 * IN_CH + 255) / 256, 256, 0, stream>>>(Wl0, Wr0, Bt0);
    prep_w<128><<<(2 * 128 * IN_CH + 255) / 256, 256, 0, stream>>>(Wl1, Wr1, Bt1);
    prep_w<64><<<(2 * 64 * IN_CH + 255) / 256, 256, 0, stream>>>(Wl2, Wr2, Bt2);

    const int GEMM_GRID = (N_NODES + 63) / 64;
    const int GATHER_GRID = (N_NODES * 64 + 255) / 256;  // one wave per node

    // ---- layer 0: x(f32) -> h(bf16) ----
    gemm_mfma<128, true, false><<<GEMM_GRID, 256, 0, stream>>>(
        x, Bt0, b0, pl, pr, N_NODES);
    gather128_bf16_kernel<<<GATHER_GRID, 256, 0, stream>>>(
        offs, ebuf, (const ushort_t*)pl, pr, h, N_NODES);

    // ---- layer 1: h(bf16) -> h(bf16) ----
    gemm_mfma<128, false, false><<<GEMM_GRID, 256, 0, stream>>>(
        h, Bt1, b1, pl, pr, N_NODES);
    gather128_bf16_kernel<<<GATHER_GRID, 256, 0, stream>>>(
        offs, ebuf, (const ushort_t*)pl, pr, h, N_NODES);

    // ---- layer 2: h(bf16) -> out(f32), pl f32 ----
    gemm_mfma<64, false, true><<<GEMM_GRID, 256, 0, stream>>>(
        h, Bt2, b2, pl, pr, N_NODES);
    gather64_kernel<<<GATHER_GRID, 256, 0, stream>>>(offs, ebuf, pl, pr, out, N_NODES);
}

// Round 6
// 251.100 us; speedup vs baseline: 15.8000x; 1.2245x over previous
//
#include <hip/hip_runtime.h>
#include <math.h>

#define N_NODES 50000
#define N_EDGES 800000
#define IN_CH 128
#define NBUCK 196        // ceil(50000/256): bucket = 256 consecutive dst nodes
#define BCAP 5120        // per-bucket capacity (mean 4096, sigma~64 -> +16 sigma)
#define EPB 4082         // edges per binA block: 196*4082 >= 800000

typedef unsigned short ushort_t;
typedef unsigned int uint_t;
typedef __attribute__((ext_vector_type(8))) short bf16x8;
typedef __attribute__((ext_vector_type(4))) float f32x4;

static __device__ __forceinline__ ushort_t f32_to_bf16(float f) {
    uint_t u = __float_as_uint(f);
    uint_t r = (u + 0x7fffu + ((u >> 16) & 1u)) >> 16;  // RNE
    return (ushort_t)r;
}
static __device__ __forceinline__ float bf16_to_f32(ushort_t u) {
    return __uint_as_float(((uint_t)u) << 16);
}

static __device__ __forceinline__ bf16x8 cvt8(const float* __restrict__ p) {
    float4 lo = *(const float4*)p;
    float4 hi = *(const float4*)(p + 4);
    bf16x8 r;
    r[0] = (short)f32_to_bf16(lo.x); r[1] = (short)f32_to_bf16(lo.y);
    r[2] = (short)f32_to_bf16(lo.z); r[3] = (short)f32_to_bf16(lo.w);
    r[4] = (short)f32_to_bf16(hi.x); r[5] = (short)f32_to_bf16(hi.y);
    r[6] = (short)f32_to_bf16(hi.z); r[7] = (short)f32_to_bf16(hi.w);
    return r;
}

// ---------------------------------------------------------------------------
// Phase A: bin edges into 196 dst-range buckets. Packed pair = (dst&255)<<16|src
// (src < 2^16). LDS staging -> chunked, mostly-coalesced bucket writes.
// ---------------------------------------------------------------------------
__global__ __launch_bounds__(256) void binA(
    const int* __restrict__ src, const int* __restrict__ dst,
    uint_t* __restrict__ gbcnt, uint_t* __restrict__ gbuck) {
    __shared__ uint_t hist[NBUCK];
    __shared__ uint_t excl_s[NBUCK];
    __shared__ uint_t gbase[NBUCK];
    __shared__ uint_t cur[NBUCK];
    __shared__ uint_t pfx[256];
    __shared__ uint_t stage[4096];
    __shared__ uint_t gpos[4096];
    const int t = threadIdx.x;
    const int e0 = blockIdx.x * EPB;
    const int e1 = min(e0 + EPB, N_EDGES);

    for (int i = t; i < NBUCK; i += 256) hist[i] = 0;
    __syncthreads();
    // pass 1: bucket histogram
    for (int e = e0 + t; e < e1; e += 256) atomicAdd(&hist[dst[e] >> 8], 1u);
    __syncthreads();
    // exclusive prefix over buckets
    uint_t own = (t < NBUCK) ? hist[t] : 0;
    pfx[t] = own;
    __syncthreads();
    for (int d = 1; d < 256; d <<= 1) {
        uint_t v = (t >= d) ? pfx[t - d] : 0;
        __syncthreads();
        pfx[t] += v;
        __syncthreads();
    }
    if (t < NBUCK) {
        uint_t excl = pfx[t] - own;
        excl_s[t] = excl;
        cur[t] = excl;
        gbase[t] = atomicAdd(&gbcnt[t], own);  // reserve chunk in bucket
    }
    __syncthreads();
    // pass 2: place into LDS staging, record global position
    for (int e = e0 + t; e < e1; e += 256) {
        int d_ = dst[e];
        int b = d_ >> 8;
        uint_t p = atomicAdd(&cur[b], 1u);
        stage[p] = ((uint_t)(d_ & 255) << 16) | (uint_t)src[e];
        gpos[p] = (uint_t)b * BCAP + gbase[b] + (p - excl_s[b]);
    }
    __syncthreads();
    // pass 3: write out (consecutive staged entries -> consecutive bucket slots)
    const int n = e1 - e0;
    for (int i = t; i < n; i += 256) gbuck[gpos[i]] = stage[i];
}

// ---------------------------------------------------------------------------
// Phase B1: per-bucket node-degree histogram -> degi (coalesced, no init needed)
// ---------------------------------------------------------------------------
__global__ __launch_bounds__(256) void binB1(
    const uint_t* __restrict__ gbcnt, const uint_t* __restrict__ gbuck,
    int* __restrict__ degi) {
    __shared__ uint_t h[256];
    const int b = blockIdx.x;
    const int t = threadIdx.x;
    h[t] = 0;
    __syncthreads();
    const uint_t n = gbcnt[b];
    const uint_t* p = &gbuck[(size_t)b * BCAP];
    for (uint_t i = t; i < n; i += 256) atomicAdd(&h[(p[i] >> 16) & 255u], 1u);
    __syncthreads();
    int node = b * 256 + t;
    if (node < N_NODES) degi[node] = (int)h[t];
}

// ---------------------------------------------------------------------------
// multi-block exclusive scan of degrees -> offs
// ---------------------------------------------------------------------------
__global__ __launch_bounds__(256) void scan_p1(const int* __restrict__ degi,
                                               int* __restrict__ bsum, int n) {
    __shared__ int s[256];
    const int t = threadIdx.x;
    const int i = blockIdx.x * 256 + t;
    s[t] = (i < n) ? degi[i] : 0;
    __syncthreads();
    for (int d = 128; d > 0; d >>= 1) {
        if (t < d) s[t] += s[t + d];
        __syncthreads();
    }
    if (t == 0) bsum[blockIdx.x] = s[0];
}

__global__ __launch_bounds__(256) void scan_p2(int* __restrict__ bsum, int nb) {
    __shared__ int s[256];
    const int t = threadIdx.x;
    int v = (t < nb) ? bsum[t] : 0;
    s[t] = v;
    __syncthreads();
    for (int d = 1; d < 256; d <<= 1) {
        int u = (t >= d) ? s[t - d] : 0;
        __syncthreads();
        s[t] += u;
        __syncthreads();
    }
    if (t < nb) bsum[t] = s[t] - v;  // exclusive
}

__global__ __launch_bounds__(256) void scan_p3(const int* __restrict__ degi,
                                               const int* __restrict__ bsum,
                                               int* __restrict__ offs, int n) {
    __shared__ int s[256];
    const int t = threadIdx.x;
    const int i = blockIdx.x * 256 + t;
    int v = (i < n) ? degi[i] : 0;
    s[t] = v;
    __syncthreads();
    for (int d = 1; d < 256; d <<= 1) {
        int u = (t >= d) ? s[t - d] : 0;
        __syncthreads();
        s[t] += u;
        __syncthreads();
    }
    if (i < n) offs[i] = s[t] - v + bsum[blockIdx.x];
    if (i == 0) offs[n] = N_EDGES;
}

// ---------------------------------------------------------------------------
// Phase B2: per bucket, LDS-cursor place srcs, sequential coalesced ebuf write
// (bucket's CSR spans are one contiguous ebuf range).
// ---------------------------------------------------------------------------
__global__ __launch_bounds__(256) void binB2(
    const uint_t* __restrict__ gbcnt, const uint_t* __restrict__ gbuck,
    const int* __restrict__ offs, int* __restrict__ ebuf) {
    __shared__ int cur[256];
    __shared__ int stage[BCAP];
    const int b = blockIdx.x;
    const int t = threadIdx.x;
    const int node = b * 256 + t;
    const int obase = offs[b * 256];
    cur[t] = (node < N_NODES) ? (offs[node] - obase) : 0;
    __syncthreads();
    const uint_t n = gbcnt[b];
    const uint_t* p = &gbuck[(size_t)b * BCAP];
    for (uint_t i = t; i < n; i += 256) {
        uint_t pr_ = p[i];
        int l = (pr_ >> 16) & 255;
        int pos = atomicAdd(&cur[l], 1);
        stage[pos] = (int)(pr_ & 0xFFFFu);
    }
    __syncthreads();
    for (uint_t i = t; i < n; i += 256) ebuf[obase + (int)i] = stage[i];
}

// ---------------------------------------------------------------------------
// weight prep: Bt[c][k] = bf16( c < D ? Wl[k][c] : Wr[k][c-D] ), K-contiguous
// ---------------------------------------------------------------------------
template <int D_OUT>
__global__ __launch_bounds__(256) void prep_w(const float* __restrict__ Wl,
                                              const float* __restrict__ Wr,
                                              ushort_t* __restrict__ Bt) {
    int i = blockIdx.x * 256 + threadIdx.x;
    if (i >= 2 * D_OUT * IN_CH) return;
    int c = i / IN_CH, k = i % IN_CH;
    float v = (c < D_OUT) ? Wl[(size_t)k * D_OUT + c] : Wr[(size_t)k * D_OUT + (c - D_OUT)];
    Bt[i] = f32_to_bf16(v);
}

// ---------------------------------------------------------------------------
// MFMA double GEMM: [64 nodes] x [2*D_OUT cols (Wl||Wr)] per block, 4 waves.
// ---------------------------------------------------------------------------
template <int D_OUT, bool IN_F32, bool PL_F32>
__global__ __launch_bounds__(256) void gemm_mfma(
    const void* __restrict__ in_v, const ushort_t* __restrict__ Bt,
    const float* __restrict__ bias,
    void* __restrict__ pl_v, float* __restrict__ pr, int nNodes) {
    constexpr int C = 2 * D_OUT;
    constexpr int SLAB = C / 4;    // cols per wave
    constexpr int NI = SLAB / 16;  // 16-col subtiles per wave
    const int tid = threadIdx.x;
    const int wave = tid >> 6, lane = tid & 63;
    const int node0 = blockIdx.x * 64;
    const int wcol0 = wave * SLAB;
    const int lrow = lane & 15;
    const int lgrp = lane >> 4;

    const ushort_t* inb = (const ushort_t*)in_v;
    const float* inf = (const float*)in_v;

    f32x4 acc[4][NI] = {};

    for (int ks = 0; ks < 4; ++ks) {
        const int k0 = ks * 32 + lgrp * 8;
        bf16x8 a[4];
#pragma unroll
        for (int mi = 0; mi < 4; ++mi) {
            int r = node0 + mi * 16 + lrow;
            r = min(r, nNodes - 1);
            if (IN_F32) {
                a[mi] = cvt8(&inf[(size_t)r * IN_CH + k0]);
            } else {
                a[mi] = *(const bf16x8*)&inb[(size_t)r * IN_CH + k0];
            }
        }
        bf16x8 bf[NI];
#pragma unroll
        for (int ni = 0; ni < NI; ++ni) {
            int c = wcol0 + ni * 16 + lrow;
            bf[ni] = *(const bf16x8*)&Bt[(size_t)c * IN_CH + k0];
        }
#pragma unroll
        for (int mi = 0; mi < 4; ++mi)
#pragma unroll
            for (int ni = 0; ni < NI; ++ni)
                acc[mi][ni] = __builtin_amdgcn_mfma_f32_16x16x32_bf16(
                    a[mi], bf[ni], acc[mi][ni], 0, 0, 0);
    }

    // epilogue: C/D layout col=lane&15, row=(lane>>4)*4+reg (m89-verified)
    const bool is_pr = (wcol0 >= D_OUT);  // wave-uniform
#pragma unroll
    for (int ni = 0; ni < NI; ++ni) {
        const int c = wcol0 + ni * 16 + lrow;
        const float bv = is_pr ? bias[c - D_OUT] : 0.f;
#pragma unroll
        for (int mi = 0; mi < 4; ++mi) {
#pragma unroll
            for (int j = 0; j < 4; ++j) {
                int r = node0 + mi * 16 + lgrp * 4 + j;
                if (r >= nNodes) continue;
                float v = acc[mi][ni][j];
                if (is_pr) {
                    pr[(size_t)r * D_OUT + (c - D_OUT)] = v + bv;
                } else if (PL_F32) {
                    ((float*)pl_v)[(size_t)r * D_OUT + c] = v;
                } else {
                    ((ushort_t*)pl_v)[(size_t)r * D_OUT + c] = f32_to_bf16(v);
                }
            }
        }
    }
}

// ---------------------------------------------------------------------------
// gather + finalize, D=128, pl bf16, h output bf16: one wave per dst node.
// ---------------------------------------------------------------------------
__global__ __launch_bounds__(256) void gather128_bf16_kernel(
    const int* __restrict__ offs, const int* __restrict__ ebuf,
    const ushort_t* __restrict__ pl, const float* __restrict__ pr,
    ushort_t* __restrict__ out, int nNodes) {
    const int wid = (int)((blockIdx.x * 256u + threadIdx.x) >> 6);
    const int lane = threadIdx.x & 63;
    if (wid >= nNodes) return;
    const int o0 = offs[wid], o1 = offs[wid + 1];
    const float inv = 1.0f / fmaxf((float)(o1 - o0), 1.0f);
    const int c = lane * 2;

    float ax0 = 0, ay0 = 0, ax1 = 0, ay1 = 0, ax2 = 0, ay2 = 0, ax3 = 0, ay3 = 0;
    int j = o0;
    for (; j + 4 <= o1; j += 4) {
        int s0 = ebuf[j], s1 = ebuf[j + 1], s2 = ebuf[j + 2], s3 = ebuf[j + 3];
        uint_t v0 = *(const uint_t*)&pl[(size_t)s0 * 128 + c];
        uint_t v1 = *(const uint_t*)&pl[(size_t)s1 * 128 + c];
        uint_t v2 = *(const uint_t*)&pl[(size_t)s2 * 128 + c];
        uint_t v3 = *(const uint_t*)&pl[(size_t)s3 * 128 + c];
        ax0 += __uint_as_float(v0 << 16); ay0 += __uint_as_float(v0 & 0xffff0000u);
        ax1 += __uint_as_float(v1 << 16); ay1 += __uint_as_float(v1 & 0xffff0000u);
        ax2 += __uint_as_float(v2 << 16); ay2 += __uint_as_float(v2 & 0xffff0000u);
        ax3 += __uint_as_float(v3 << 16); ay3 += __uint_as_float(v3 & 0xffff0000u);
    }
    for (; j < o1; ++j) {
        uint_t v0 = *(const uint_t*)&pl[(size_t)ebuf[j] * 128 + c];
        ax0 += __uint_as_float(v0 << 16);
        ay0 += __uint_as_float(v0 & 0xffff0000u);
    }
    float vx = (ax0 + ax1 + ax2 + ax3) * inv + pr[(size_t)wid * 128 + c];
    float vy = (ay0 + ay1 + ay2 + ay3) * inv + pr[(size_t)wid * 128 + c + 1];
    vx = vx > 0.f ? vx : expm1f(vx);
    vy = vy > 0.f ? vy : expm1f(vy);
    uint_t packed = (uint_t)f32_to_bf16(vx) | ((uint_t)f32_to_bf16(vy) << 16);
    *(uint_t*)&out[(size_t)wid * 128 + c] = packed;
}

// ---------------------------------------------------------------------------
// gather + finalize, D=64, pl bf16, f32 out, no ELU (last layer)
// ---------------------------------------------------------------------------
__global__ __launch_bounds__(256) void gather64_bf16_kernel(
    const int* __restrict__ offs, const int* __restrict__ ebuf,
    const ushort_t* __restrict__ pl, const float* __restrict__ pr,
    float* __restrict__ out, int nNodes) {
    const int wid = (int)((blockIdx.x * 256u + threadIdx.x) >> 6);
    const int lane = threadIdx.x & 63;
    if (wid >= nNodes) return;
    const int o0 = offs[wid], o1 = offs[wid + 1];
    const float inv = 1.0f / fmaxf((float)(o1 - o0), 1.0f);
    const int c = lane;
    float a0 = 0, a1 = 0, a2 = 0, a3 = 0;
    int j = o0;
    for (; j + 4 <= o1; j += 4) {
        int s0 = ebuf[j], s1 = ebuf[j + 1], s2 = ebuf[j + 2], s3 = ebuf[j + 3];
        a0 += bf16_to_f32(pl[(size_t)s0 * 64 + c]);
        a1 += bf16_to_f32(pl[(size_t)s1 * 64 + c]);
        a2 += bf16_to_f32(pl[(size_t)s2 * 64 + c]);
        a3 += bf16_to_f32(pl[(size_t)s3 * 64 + c]);
    }
    for (; j < o1; ++j) a0 += bf16_to_f32(pl[(size_t)ebuf[j] * 64 + c]);
    float v = (a0 + a1 + a2 + a3) * inv + pr[(size_t)wid * 64 + c];
    out[(size_t)wid * 64 + c] = v;
}

// ---------------------------------------------------------------------------
extern "C" void kernel_launch(void* const* d_in, const int* in_sizes, int n_in,
                              void* d_out, int out_size, void* d_ws, size_t ws_size,
                              hipStream_t stream) {
    const float* x = (const float*)d_in[0];
    const int* ei = (const int*)d_in[1];
    const int* src = ei;
    const int* dst = ei + N_EDGES;
    const float* Wl0 = (const float*)d_in[2];
    const float* Wr0 = (const float*)d_in[3];
    const float* b0 = (const float*)d_in[4];
    const float* Wl1 = (const float*)d_in[5];
    const float* Wr1 = (const float*)d_in[6];
    const float* b1 = (const float*)d_in[7];
    const float* Wl2 = (const float*)d_in[8];
    const float* Wr2 = (const float*)d_in[9];
    const float* b2 = (const float*)d_in[10];
    float* out = (float*)d_out;

    // workspace layout (int units)
    int* wsi = (int*)d_ws;
    int* degi = wsi;                               // 51200
    int* offs = degi + 51200;                      // 51200
    int* bsum = offs + 51200;                      // 256
    uint_t* gbcnt = (uint_t*)(bsum + 256);         // 256
    int* ebuf = (int*)(gbcnt + 256);               // 800000
    uint_t* gbuck = (uint_t*)(ebuf + 800000);      // NBUCK*BCAP = 1,003,520
    ushort_t* Bt0 = (ushort_t*)(gbuck + NBUCK * BCAP);  // 256*128 bf16
    ushort_t* Bt1 = Bt0 + 256 * 128;
    ushort_t* Bt2 = Bt1 + 256 * 128;               // 128*128
    float* pl = (float*)(Bt2 + 128 * 128);         // [N*128] f32 (bf16 uses half)
    const long long NB = (long long)N_NODES * 128;
    float* pr = pl + NB;                           // [N*128] f32
    ushort_t* h = (ushort_t*)(pr + NB);            // [N*128] bf16

    const int NSB = (N_NODES + 255) / 256;         // 196

    // ---- build CSR via bucketed two-phase scatter ----
    hipMemsetAsync(gbcnt, 0, NBUCK * sizeof(uint_t), stream);
    binA<<<NBUCK, 256, 0, stream>>>(src, dst, gbcnt, gbuck);
    binB1<<<NBUCK, 256, 0, stream>>>(gbcnt, gbuck, degi);
    scan_p1<<<NSB, 256, 0, stream>>>(degi, bsum, N_NODES);
    scan_p2<<<1, 256, 0, stream>>>(bsum, NSB);
    scan_p3<<<NSB, 256, 0, stream>>>(degi, bsum, offs, N_NODES);
    binB2<<<NBUCK, 256, 0, stream>>>(gbcnt, gbuck, offs, ebuf);

    // ---- pack weights to bf16 K-contiguous ----
    prep_w<128><<<(2 * 128 * IN_CH + 255) / 256, 256, 0, stream>>>(Wl0, Wr0, Bt0);
    prep_w<128><<<(2 * 128 * IN_CH + 255) / 256, 256, 0, stream>>>(Wl1, Wr1, Bt1);
    prep_w<64><<<(2 * 64 * IN_CH + 255) / 256, 256, 0, stream>>>(Wl2, Wr2, Bt2);

    const int GEMM_GRID = (N_NODES + 63) / 64;
    const int GATHER_GRID = (N_NODES * 64 + 255) / 256;  // one wave per node

    // ---- layer 0: x(f32) -> h(bf16) ----
    gemm_mfma<128, true, false><<<GEMM_GRID, 256, 0, stream>>>(
        x, Bt0, b0, pl, pr, N_NODES);
    gather128_bf16_kernel<<<GATHER_GRID, 256, 0, stream>>>(
        offs, ebuf, (const ushort_t*)pl, pr, h, N_NODES);

    // ---- layer 1: h(bf16) -> h(bf16) ----
    gemm_mfma<128, false, false><<<GEMM_GRID, 256, 0, stream>>>(
        h, Bt1, b1, pl, pr, N_NODES);
    gather128_bf16_kernel<<<GATHER_GRID, 256, 0, stream>>>(
        offs, ebuf, (const ushort_t*)pl, pr, h, N_NODES);

    // ---- layer 2: h(bf16) -> out(f32), pl bf16 ----
    gemm_mfma<64, false, false><<<GEMM_GRID, 256, 0, stream>>>(
        h, Bt2, b2, pl, pr, N_NODES);
    gather64_bf16_kernel<<<GATHER_GRID, 256, 0, stream>>>(
        offs, ebuf, (const ushort_t*)pl, pr, out, N_NODES);
}

// Round 7
// 248.283 us; speedup vs baseline: 15.9793x; 1.0113x over previous
//
#include <hip/hip_runtime.h>
#include <math.h>

#define N_NODES 50000
#define N_EDGES 800000
#define IN_CH 128
#define NBUCK 196        // ceil(50000/256): bucket = 256 consecutive dst nodes
#define BCAP 5120        // per-bucket capacity
#define EPB 4082         // edges per binA block: 196*4082 >= 800000

typedef unsigned short ushort_t;
typedef unsigned int uint_t;
typedef __attribute__((ext_vector_type(8))) short bf16x8;
typedef __attribute__((ext_vector_type(4))) float f32x4;

static __device__ __forceinline__ ushort_t f32_to_bf16(float f) {
    uint_t u = __float_as_uint(f);
    uint_t r = (u + 0x7fffu + ((u >> 16) & 1u)) >> 16;  // RNE
    return (ushort_t)r;
}

// ---------------------------------------------------------------------------
// Phase A: bin edges into 196 dst-range buckets. pair = (dst&255)<<16 | src
// ---------------------------------------------------------------------------
__global__ __launch_bounds__(256) void binA(
    const int* __restrict__ src, const int* __restrict__ dst,
    uint_t* __restrict__ gbcnt, uint_t* __restrict__ gbuck) {
    __shared__ uint_t hist[NBUCK];
    __shared__ uint_t excl_s[NBUCK];
    __shared__ uint_t gbase[NBUCK];
    __shared__ uint_t cur[NBUCK];
    __shared__ uint_t pfx[256];
    __shared__ uint_t stage[4096];
    __shared__ uint_t gpos[4096];
    const int t = threadIdx.x;
    const int e0 = blockIdx.x * EPB;
    const int e1 = min(e0 + EPB, N_EDGES);

    for (int i = t; i < NBUCK; i += 256) hist[i] = 0;
    __syncthreads();
    for (int e = e0 + t; e < e1; e += 256) atomicAdd(&hist[dst[e] >> 8], 1u);
    __syncthreads();
    uint_t own = (t < NBUCK) ? hist[t] : 0;
    pfx[t] = own;
    __syncthreads();
    for (int d = 1; d < 256; d <<= 1) {
        uint_t v = (t >= d) ? pfx[t - d] : 0;
        __syncthreads();
        pfx[t] += v;
        __syncthreads();
    }
    if (t < NBUCK) {
        uint_t excl = pfx[t] - own;
        excl_s[t] = excl;
        cur[t] = excl;
        gbase[t] = atomicAdd(&gbcnt[t], own);
    }
    __syncthreads();
    for (int e = e0 + t; e < e1; e += 256) {
        int d_ = dst[e];
        int b = d_ >> 8;
        uint_t p = atomicAdd(&cur[b], 1u);
        stage[p] = ((uint_t)(d_ & 255) << 16) | (uint_t)src[e];
        gpos[p] = (uint_t)b * BCAP + gbase[b] + (p - excl_s[b]);
    }
    __syncthreads();
    const int n = e1 - e0;
    for (int i = t; i < n; i += 256) gbuck[gpos[i]] = stage[i];
}

// ---------------------------------------------------------------------------
// Phase B1: per-bucket node-degree histogram -> degi
// ---------------------------------------------------------------------------
__global__ __launch_bounds__(256) void binB1(
    const uint_t* __restrict__ gbcnt, const uint_t* __restrict__ gbuck,
    int* __restrict__ degi) {
    __shared__ uint_t h[256];
    const int b = blockIdx.x;
    const int t = threadIdx.x;
    h[t] = 0;
    __syncthreads();
    const uint_t n = gbcnt[b];
    const uint_t* p = &gbuck[(size_t)b * BCAP];
    for (uint_t i = t; i < n; i += 256) atomicAdd(&h[(p[i] >> 16) & 255u], 1u);
    __syncthreads();
    int node = b * 256 + t;
    if (node < N_NODES) degi[node] = (int)h[t];
}

// ---------------------------------------------------------------------------
// multi-block exclusive scan of degrees -> offs
// ---------------------------------------------------------------------------
__global__ __launch_bounds__(256) void scan_p1(const int* __restrict__ degi,
                                               int* __restrict__ bsum, int n) {
    __shared__ int s[256];
    const int t = threadIdx.x;
    const int i = blockIdx.x * 256 + t;
    s[t] = (i < n) ? degi[i] : 0;
    __syncthreads();
    for (int d = 128; d > 0; d >>= 1) {
        if (t < d) s[t] += s[t + d];
        __syncthreads();
    }
    if (t == 0) bsum[blockIdx.x] = s[0];
}

__global__ __launch_bounds__(256) void scan_p2(int* __restrict__ bsum, int nb) {
    __shared__ int s[256];
    const int t = threadIdx.x;
    int v = (t < nb) ? bsum[t] : 0;
    s[t] = v;
    __syncthreads();
    for (int d = 1; d < 256; d <<= 1) {
        int u = (t >= d) ? s[t - d] : 0;
        __syncthreads();
        s[t] += u;
        __syncthreads();
    }
    if (t < nb) bsum[t] = s[t] - v;  // exclusive
}

__global__ __launch_bounds__(256) void scan_p3(const int* __restrict__ degi,
                                               const int* __restrict__ bsum,
                                               int* __restrict__ offs, int n) {
    __shared__ int s[256];
    const int t = threadIdx.x;
    const int i = blockIdx.x * 256 + t;
    int v = (i < n) ? degi[i] : 0;
    s[t] = v;
    __syncthreads();
    for (int d = 1; d < 256; d <<= 1) {
        int u = (t >= d) ? s[t - d] : 0;
        __syncthreads();
        s[t] += u;
        __syncthreads();
    }
    if (i < n) offs[i] = s[t] - v + bsum[blockIdx.x];
    if (i == 0) offs[n] = N_EDGES;
}

// ---------------------------------------------------------------------------
// Phase B2: per bucket, LDS-cursor place srcs, sequential coalesced ebuf write
// ---------------------------------------------------------------------------
__global__ __launch_bounds__(256) void binB2(
    const uint_t* __restrict__ gbcnt, const uint_t* __restrict__ gbuck,
    const int* __restrict__ offs, int* __restrict__ ebuf) {
    __shared__ int cur[256];
    __shared__ int stage[BCAP];
    const int b = blockIdx.x;
    const int t = threadIdx.x;
    const int node = b * 256 + t;
    const int obase = offs[b * 256];
    cur[t] = (node < N_NODES) ? (offs[node] - obase) : 0;
    __syncthreads();
    const uint_t n = gbcnt[b];
    const uint_t* p = &gbuck[(size_t)b * BCAP];
    for (uint_t i = t; i < n; i += 256) {
        uint_t pr_ = p[i];
        int l = (pr_ >> 16) & 255;
        int pos = atomicAdd(&cur[l], 1);
        stage[pos] = (int)(pr_ & 0xFFFFu);
    }
    __syncthreads();
    for (uint_t i = t; i < n; i += 256) ebuf[obase + (int)i] = stage[i];
}

// ---------------------------------------------------------------------------
// convert x f32 -> bf16 (one pass)
// ---------------------------------------------------------------------------
__global__ __launch_bounds__(256) void cvt_x(const float* __restrict__ x,
                                             ushort_t* __restrict__ xb, int n8) {
    int i = blockIdx.x * 256 + threadIdx.x;
    if (i >= n8) return;
    const float* p = x + (size_t)i * 8;
    float4 lo = *(const float4*)p;
    float4 hi = *(const float4*)(p + 4);
    bf16x8 r;
    r[0] = (short)f32_to_bf16(lo.x); r[1] = (short)f32_to_bf16(lo.y);
    r[2] = (short)f32_to_bf16(lo.z); r[3] = (short)f32_to_bf16(lo.w);
    r[4] = (short)f32_to_bf16(hi.x); r[5] = (short)f32_to_bf16(hi.y);
    r[6] = (short)f32_to_bf16(hi.z); r[7] = (short)f32_to_bf16(hi.w);
    *(bf16x8*)&xb[(size_t)i * 8] = r;
}

// ---------------------------------------------------------------------------
// weight prep: stacked Bt[c][k], k in [0,256): k<128 -> Wl[k][c], else Wr[k-128][c]
// ---------------------------------------------------------------------------
template <int C>
__global__ __launch_bounds__(256) void prep_w(const float* __restrict__ Wl,
                                              const float* __restrict__ Wr,
                                              ushort_t* __restrict__ Bt) {
    int i = blockIdx.x * 256 + threadIdx.x;
    if (i >= C * 256) return;
    int c = i / 256, k = i % 256;
    float v = (k < 128) ? Wl[(size_t)k * C + c] : Wr[(size_t)(k - 128) * C + c];
    Bt[i] = f32_to_bf16(v);
}

// ---------------------------------------------------------------------------
// mean-aggregate gather: M[node] = mean(feat[neighbors]) (bf16 in, bf16 out)
// one wave per dst node, lane owns 2 channels.
// ---------------------------------------------------------------------------
__global__ __launch_bounds__(256) void gather_mean(
    const int* __restrict__ offs, const int* __restrict__ ebuf,
    const ushort_t* __restrict__ feat, ushort_t* __restrict__ M, int nNodes) {
    const int wid = (int)((blockIdx.x * 256u + threadIdx.x) >> 6);
    const int lane = threadIdx.x & 63;
    if (wid >= nNodes) return;
    const int o0 = offs[wid], o1 = offs[wid + 1];
    const float inv = 1.0f / fmaxf((float)(o1 - o0), 1.0f);
    const int c = lane * 2;

    float ax0 = 0, ay0 = 0, ax1 = 0, ay1 = 0, ax2 = 0, ay2 = 0, ax3 = 0, ay3 = 0;
    int j = o0;
    for (; j + 4 <= o1; j += 4) {
        int s0 = ebuf[j], s1 = ebuf[j + 1], s2 = ebuf[j + 2], s3 = ebuf[j + 3];
        uint_t v0 = *(const uint_t*)&feat[(size_t)s0 * 128 + c];
        uint_t v1 = *(const uint_t*)&feat[(size_t)s1 * 128 + c];
        uint_t v2 = *(const uint_t*)&feat[(size_t)s2 * 128 + c];
        uint_t v3 = *(const uint_t*)&feat[(size_t)s3 * 128 + c];
        ax0 += __uint_as_float(v0 << 16); ay0 += __uint_as_float(v0 & 0xffff0000u);
        ax1 += __uint_as_float(v1 << 16); ay1 += __uint_as_float(v1 & 0xffff0000u);
        ax2 += __uint_as_float(v2 << 16); ay2 += __uint_as_float(v2 & 0xffff0000u);
        ax3 += __uint_as_float(v3 << 16); ay3 += __uint_as_float(v3 & 0xffff0000u);
    }
    for (; j < o1; ++j) {
        uint_t v0 = *(const uint_t*)&feat[(size_t)ebuf[j] * 128 + c];
        ax0 += __uint_as_float(v0 << 16);
        ay0 += __uint_as_float(v0 & 0xffff0000u);
    }
    float vx = (ax0 + ax1 + ax2 + ax3) * inv;
    float vy = (ay0 + ay1 + ay2 + ay3) * inv;
    uint_t packed = (uint_t)f32_to_bf16(vx) | ((uint_t)f32_to_bf16(vy) << 16);
    *(uint_t*)&M[(size_t)wid * 128 + c] = packed;
}

// ---------------------------------------------------------------------------
// fused GEMM: out = [M | X] @ Bt^T + bias  (K=256), optional ELU, bf16/f32 out.
// block = 64 rows x 64 cols, 4 waves as 2x2 of 32x32 tiles.
// ---------------------------------------------------------------------------
template <int C, bool ELU, bool OUT_F32>
__global__ __launch_bounds__(256) void gemm_fused(
    const ushort_t* __restrict__ M, const ushort_t* __restrict__ X,
    const ushort_t* __restrict__ Bt, const float* __restrict__ bias,
    void* __restrict__ out_v, int nNodes) {
    const int tid = threadIdx.x;
    const int wave = tid >> 6, lane = tid & 63;
    const int lrow = lane & 15, lgrp = lane >> 4;
    const int rowbase = blockIdx.x * 64 + (wave >> 1) * 32;
    const int colbase = blockIdx.y * 64 + (wave & 1) * 32;

    f32x4 acc[2][2] = {};

#pragma unroll
    for (int half = 0; half < 2; ++half) {
        const ushort_t* A = half ? X : M;
#pragma unroll
        for (int ks = 0; ks < 4; ++ks) {
            const int k0 = ks * 32 + lgrp * 8;
            bf16x8 a[2], bf[2];
#pragma unroll
            for (int mi = 0; mi < 2; ++mi) {
                int r = rowbase + mi * 16 + lrow;
                r = min(r, nNodes - 1);
                a[mi] = *(const bf16x8*)&A[(size_t)r * 128 + k0];
            }
#pragma unroll
            for (int ni = 0; ni < 2; ++ni) {
                int c = colbase + ni * 16 + lrow;
                bf[ni] = *(const bf16x8*)&Bt[(size_t)c * 256 + half * 128 + k0];
            }
#pragma unroll
            for (int mi = 0; mi < 2; ++mi)
#pragma unroll
                for (int ni = 0; ni < 2; ++ni)
                    acc[mi][ni] = __builtin_amdgcn_mfma_f32_16x16x32_bf16(
                        a[mi], bf[ni], acc[mi][ni], 0, 0, 0);
        }
    }

    // epilogue: C/D layout col=lane&15, row=(lane>>4)*4+reg (m89-verified)
#pragma unroll
    for (int ni = 0; ni < 2; ++ni) {
        const int c = colbase + ni * 16 + lrow;
        const float bv = bias[c];
#pragma unroll
        for (int mi = 0; mi < 2; ++mi) {
#pragma unroll
            for (int j = 0; j < 4; ++j) {
                int r = rowbase + mi * 16 + lgrp * 4 + j;
                if (r >= nNodes) continue;
                float v = acc[mi][ni][j] + bv;
                if (ELU) v = v > 0.f ? v : expm1f(v);
                if (OUT_F32) ((float*)out_v)[(size_t)r * C + c] = v;
                else ((ushort_t*)out_v)[(size_t)r * C + c] = f32_to_bf16(v);
            }
        }
    }
}

// ---------------------------------------------------------------------------
extern "C" void kernel_launch(void* const* d_in, const int* in_sizes, int n_in,
                              void* d_out, int out_size, void* d_ws, size_t ws_size,
                              hipStream_t stream) {
    const float* x = (const float*)d_in[0];
    const int* ei = (const int*)d_in[1];
    const int* src = ei;
    const int* dst = ei + N_EDGES;
    const float* Wl0 = (const float*)d_in[2];
    const float* Wr0 = (const float*)d_in[3];
    const float* b0 = (const float*)d_in[4];
    const float* Wl1 = (const float*)d_in[5];
    const float* Wr1 = (const float*)d_in[6];
    const float* b1 = (const float*)d_in[7];
    const float* Wl2 = (const float*)d_in[8];
    const float* Wr2 = (const float*)d_in[9];
    const float* b2 = (const float*)d_in[10];
    float* out = (float*)d_out;

    // workspace layout (int units)
    int* wsi = (int*)d_ws;
    int* degi = wsi;                               // 51200
    int* offs = degi + 51200;                      // 51200
    int* bsum = offs + 51200;                      // 256
    uint_t* gbcnt = (uint_t*)(bsum + 256);         // 256
    int* ebuf = (int*)(gbcnt + 256);               // 800000
    uint_t* gbuck = (uint_t*)(ebuf + 800000);      // NBUCK*BCAP = 1,003,520
    ushort_t* Bt0 = (ushort_t*)(gbuck + NBUCK * BCAP);  // 128*256
    ushort_t* Bt1 = Bt0 + 128 * 256;                    // 128*256
    ushort_t* Bt2 = Bt1 + 128 * 256;                    // 64*256
    const long long NB = (long long)N_NODES * 128;
    ushort_t* xb = Bt2 + 64 * 256;                 // [N*128] bf16
    ushort_t* Mb = xb + NB;                        // [N*128] bf16
    ushort_t* hA = Mb + NB;                        // [N*128] bf16
    ushort_t* hB = hA + NB;                        // [N*128] bf16

    const int NSB = (N_NODES + 255) / 256;         // 196

    // ---- build CSR via bucketed two-phase scatter ----
    hipMemsetAsync(gbcnt, 0, NBUCK * sizeof(uint_t), stream);
    binA<<<NBUCK, 256, 0, stream>>>(src, dst, gbcnt, gbuck);
    binB1<<<NBUCK, 256, 0, stream>>>(gbcnt, gbuck, degi);
    scan_p1<<<NSB, 256, 0, stream>>>(degi, bsum, N_NODES);
    scan_p2<<<1, 256, 0, stream>>>(bsum, NSB);
    scan_p3<<<NSB, 256, 0, stream>>>(degi, bsum, offs, N_NODES);
    binB2<<<NBUCK, 256, 0, stream>>>(gbcnt, gbuck, offs, ebuf);

    // ---- prep: x->bf16, stacked bf16 weights ----
    cvt_x<<<(N_NODES * 16 + 255) / 256, 256, 0, stream>>>(x, xb, N_NODES * 16);
    prep_w<128><<<(128 * 256 + 255) / 256, 256, 0, stream>>>(Wl0, Wr0, Bt0);
    prep_w<128><<<(128 * 256 + 255) / 256, 256, 0, stream>>>(Wl1, Wr1, Bt1);
    prep_w<64><<<(64 * 256 + 255) / 256, 256, 0, stream>>>(Wl2, Wr2, Bt2);

    const int GATHER_GRID = (N_NODES * 64 + 255) / 256;  // one wave per node
    const int GR = (N_NODES + 63) / 64;                  // 782 row panels

    // ---- layer 0: M=agg(xb); hA = ELU([M|xb]@[Wl0;Wr0]+b0) ----
    gather_mean<<<GATHER_GRID, 256, 0, stream>>>(offs, ebuf, xb, Mb, N_NODES);
    gemm_fused<128, true, false><<<dim3(GR, 2), 256, 0, stream>>>(
        Mb, xb, Bt0, b0, hA, N_NODES);

    // ---- layer 1: M=agg(hA); hB = ELU([M|hA]@[Wl1;Wr1]+b1) ----
    gather_mean<<<GATHER_GRID, 256, 0, stream>>>(offs, ebuf, hA, Mb, N_NODES);
    gemm_fused<128, true, false><<<dim3(GR, 2), 256, 0, stream>>>(
        Mb, hA, Bt1, b1, hB, N_NODES);

    // ---- layer 2: M=agg(hB); out = [M|hB]@[Wl2;Wr2]+b2 (f32) ----
    gather_mean<<<GATHER_GRID, 256, 0, stream>>>(offs, ebuf, hB, Mb, N_NODES);
    gemm_fused<64, false, true><<<dim3(GR, 1), 256, 0, stream>>>(
        Mb, hB, Bt2, b2, out, N_NODES);
}